// Round 24
// baseline (484.426 us; speedup 1.0000x reference)
//
#include <hip/hip_runtime.h>

#define N_NODES 131072
#define E_EDGES 524288
#define NGRAPH  16
#define NPG     8192
#define DIM     128
#define KSEL    4096
#define SCAN_BLOCKS 128   // N_NODES / 1024

typedef float v2f __attribute__((ext_vector_type(2)));
typedef float v4f __attribute__((ext_vector_type(4)));

// ---------------- CSR build ----------------
__global__ void count_deg_kernel(const int* __restrict__ ei, int* __restrict__ deg) {
    int e = blockIdx.x * 256 + threadIdx.x;
    atomicAdd(&deg[ei[E_EDGES + e]], 1);
}

__global__ __launch_bounds__(256) void scan_partial_kernel(const int* __restrict__ deg,
                                                           int* __restrict__ bsum) {
    __shared__ int wsh[4];
    int b = blockIdx.x, t = threadIdx.x;
    int4 v = ((const int4*)&deg[b * 1024])[t];
    int s = v.x + v.y + v.z + v.w;
#pragma unroll
    for (int off = 32; off; off >>= 1) s += __shfl_xor(s, off);
    if ((t & 63) == 0) wsh[t >> 6] = s;
    __syncthreads();
    if (t == 0) bsum[b] = wsh[0] + wsh[1] + wsh[2] + wsh[3];
}

__global__ __launch_bounds__(128) void scan_bsum_kernel(const int* __restrict__ bsum,
                                                        int* __restrict__ boff,
                                                        int* __restrict__ rowptr) {
    __shared__ int w0;
    int t = threadIdx.x;
    int lane = t & 63;
    int v = bsum[t];
    int x = v;
#pragma unroll
    for (int off = 1; off < 64; off <<= 1) {
        int y = __shfl_up(x, off);
        if (lane >= off) x += y;
    }
    if (t == 63) w0 = x;
    __syncthreads();
    int incl = x + ((t >= 64) ? w0 : 0);
    boff[t] = incl - v;
    if (t == 127) rowptr[N_NODES] = incl;
}

__global__ __launch_bounds__(256) void scan_final_kernel(const int* __restrict__ deg,
                                                         const int* __restrict__ boff,
                                                         int* __restrict__ rowptr,
                                                         int* __restrict__ cursor,
                                                         float* __restrict__ dis) {
    __shared__ int wsum[4];
    int b = blockIdx.x, t = threadIdx.x;
    int lane = t & 63, wv = t >> 6;
    int4 v = ((const int4*)&deg[b * 1024])[t];
    int s = v.x + v.y + v.z + v.w;
    int x = s;
#pragma unroll
    for (int off = 1; off < 64; off <<= 1) {
        int y = __shfl_up(x, off);
        if (lane >= off) x += y;
    }
    if (lane == 63) wsum[wv] = x;
    __syncthreads();
    int add = boff[b];
#pragma unroll
    for (int j = 0; j < 4; ++j)
        if (j < wv) add += wsum[j];
    int excl = add + (x - s);
    int base = b * 1024 + t * 4;
    int4 rp;
    rp.x = excl;
    rp.y = excl + v.x;
    rp.z = rp.y + v.y;
    rp.w = rp.z + v.z;
    *(int4*)&rowptr[base] = rp;
    *(int4*)&cursor[base] = rp;
    float4 dv;
    dv.x = rsqrtf((float)v.x + 1.0f);
    dv.y = rsqrtf((float)v.y + 1.0f);
    dv.z = rsqrtf((float)v.z + 1.0f);
    dv.w = rsqrtf((float)v.w + 1.0f);
    *(float4*)&dis[base] = dv;
}

__global__ void fill_csr_kernel(const int* __restrict__ ei, int* __restrict__ cursor,
                                const float* __restrict__ dis, int* __restrict__ csr_src,
                                float* __restrict__ csr_coef) {
    int e = blockIdx.x * 256 + threadIdx.x;
    int s = ei[e];
    int d = ei[E_EDGES + e];
    int p = atomicAdd(&cursor[d], 1);
    csr_src[p] = s;
    csr_coef[p] = dis[s] * dis[d];
}

// ---------------- node embedding: h = x @ node_w + node_b (vectorized) ------
__global__ __launch_bounds__(256) void embed_kernel(const float* __restrict__ x,
                                                    const float* __restrict__ nw,
                                                    const float* __restrict__ nb,
                                                    float* __restrict__ h) {
    __shared__ float Wl[16 * DIM];
    __shared__ float biasl[DIM];
    int t = threadIdx.x;
    for (int i = t * 4; i < 16 * DIM; i += 1024)
        *(float4*)&Wl[i] = *(const float4*)&nw[i];
    if (t < 32) ((float4*)biasl)[t] = ((const float4*)nb)[t];
    __syncthreads();
    int xslot = blockIdx.x & 7, q = blockIdx.x >> 3;   // q: 0..255
    int g = xslot + ((q >= 128) ? 8 : 0);
    int chunk = q & 127;
    int base = g * NPG + chunk * 64;
    int nl = t >> 5;            // node_local 0..7
    int d4 = t & 31;            // float4 group 0..31
    v4f bias = ((const v4f*)biasl)[d4];
    const v4f* Wl4 = (const v4f*)Wl;
    for (int k = 0; k < 8; ++k) {
        int n = base + k * 8 + nl;
        const v4f* xr = (const v4f*)&x[n * 16];
        v4f x0 = xr[0], x1 = xr[1], x2 = xr[2], x3 = xr[3];
        v4f acc = bias;
#pragma unroll
        for (int u = 0; u < 4; ++u) {
            acc += x0[u] * Wl4[(u)      * 32 + d4];
            acc += x1[u] * Wl4[(u + 4)  * 32 + d4];
            acc += x2[u] * Wl4[(u + 8)  * 32 + d4];
            acc += x3[u] * Wl4[(u + 12) * 32 + d4];
        }
        *(v4f*)&h[(size_t)n * DIM + d4 * 4] = acc;
    }
}

// ---------------- sparse propagate: m = sum coef*h[src] + dis^2 * h ----------
// r18 validated: 4-wide batched edge gathers; normal m store (r17 lesson).
__global__ __launch_bounds__(256) void agg_kernel(const float* __restrict__ h,
                                                  const int* __restrict__ rowptr,
                                                  const int* __restrict__ csr_src,
                                                  const float* __restrict__ csr_coef,
                                                  const float* __restrict__ dis,
                                                  float* __restrict__ m) {
    int bb = blockIdx.x;
    int xslot = bb & 7;
    int c = bb >> 3;                 // 0..1023
    int g = xslot + ((c >= 512) ? 8 : 0);
    int chunk = c & 511;             // 0..511
    int t = threadIdx.x;
    int nl = t >> 6, l = t & 63;
    int nbase = g * NPG + chunk * 16;
#pragma unroll
    for (int it = 0; it < 4; ++it) {
        int n = nbase + it * 4 + nl;
        float dn = dis[n];
        float2 hv = *(const float2*)&h[(size_t)n * DIM + l * 2];
        float ax = dn * dn * hv.x;
        float ay = dn * dn * hv.y;
        int e0 = rowptr[n], e1 = rowptr[n + 1];
        int e = e0;
        for (; e + 4 <= e1; e += 4) {
            int s0 = csr_src[e],     s1 = csr_src[e + 1];
            int s2 = csr_src[e + 2], s3 = csr_src[e + 3];
            float c0 = csr_coef[e],     c1 = csr_coef[e + 1];
            float c2 = csr_coef[e + 2], c3 = csr_coef[e + 3];
            float2 v0 = *(const float2*)&h[(size_t)s0 * DIM + l * 2];
            float2 v1 = *(const float2*)&h[(size_t)s1 * DIM + l * 2];
            float2 v2 = *(const float2*)&h[(size_t)s2 * DIM + l * 2];
            float2 v3 = *(const float2*)&h[(size_t)s3 * DIM + l * 2];
            ax = fmaf(c0, v0.x, fmaf(c1, v1.x, fmaf(c2, v2.x, fmaf(c3, v3.x, ax))));
            ay = fmaf(c0, v0.y, fmaf(c1, v1.y, fmaf(c2, v2.y, fmaf(c3, v3.y, ay))));
        }
        for (; e < e1; ++e) {
            int s = csr_src[e];
            float cf = csr_coef[e];
            float2 v = *(const float2*)&h[(size_t)s * DIM + l * 2];
            ax = fmaf(cf, v.x, ax);
            ay = fmaf(cf, v.y, ay);
        }
        float2 o;
        o.x = ax; o.y = ay;
        *(float2*)&m[(size_t)n * DIM + l * 2] = o;
    }
}

// ---------------- dense: h = leaky(BN(m @ W + cb)), optional fused dots ------
// r17 per-thread code at 512 threads/block, launch_bounds(512,1):
// 8 waves/block x 128 VGPR = 1024 regs; LDS 64KB x 2 blocks = 128 <= 160KB ->
// runtime 2 blocks/CU = 16 waves/CU = 4 waves/SIMD (2x the (256,2) config),
// W staged once per 256 nodes (2x amortization). Cap rule 256/arg2 -> (512,1)
// caps at 256, compiler allocates the same 128 this body always used.
// [Failure signature if the (1024,1) anomaly recurs: VGPR=64 + GB FETCH.]
__global__ __launch_bounds__(512, 1) void gemm_bn_kernel(const float* __restrict__ m,
                                                         const float* __restrict__ W,
                                                         const float* __restrict__ cb,
                                                         const float* __restrict__ bg,
                                                         const float* __restrict__ bb,
                                                         const float* __restrict__ bm,
                                                         const float* __restrict__ bv,
                                                         float* __restrict__ h,
                                                         const float* __restrict__ wr,
                                                         const float* __restrict__ ws,
                                                         const float* __restrict__ pb,
                                                         float* __restrict__ tb,
                                                         float* __restrict__ sb,
                                                         int fuse_dots) {
    __shared__ float Wl[DIM * DIM];   // 64 KB, permuted
    v4f* Wl4 = (v4f*)Wl;
    const int t = threadIdx.x;
    const int i = t >> 4;        // node group 0..31 (8 nodes each)
    const int j = t & 15;        // col group 0..15 (8 cols each)
    const int xslot = blockIdx.x & 7, q = blockIdx.x >> 3;   // q: 0..63
    const int graph = xslot + ((q >= 32) ? 8 : 0);
    const int chunk = q & 31;
    const int blockbase = graph * NPG + chunk * 256;

    // stage W permuted: dst slot = (c&1)*16 + (c>>1)
    {
        const v4f* W4 = (const v4f*)W;
#pragma unroll
        for (int p = 0; p < 8; ++p) {
            int idx = t + p * 512;
            int row = idx >> 5, c = idx & 31;
            Wl4[(row << 5) | ((c & 1) * 16 + (c >> 1))] = W4[idx];
        }
    }
    // BN consts for cols j*8 .. j*8+7
    float A[8], C[8];
#pragma unroll
    for (int c = 0; c < 8; ++c) {
        int d = j * 8 + c;
        float inv = rsqrtf(bv[d] + 1e-5f);
        float a = bg[d] * inv;
        A[c] = a;
        C[c] = (cb[d] - bm[d]) * a + bb[d];
    }
    float wrf[8], wsf[8];
    float pb0 = 0.f;
    if (fuse_dots) {
        *(float4*)&wrf[0] = ((const float4*)wr)[j * 2];
        *(float4*)&wrf[4] = ((const float4*)wr)[j * 2 + 1];
        *(float4*)&wsf[0] = ((const float4*)ws)[j * 2];
        *(float4*)&wsf[4] = ((const float4*)ws)[j * 2 + 1];
        pb0 = pb[0];
    }
    __syncthreads();

    const float* mrow = &m[(size_t)(blockbase + i * 8) * DIM];  // 8 rows, stride DIM

    float acc[8][8] = {{0.f}};
    v4f a0[8], a1[8];
#pragma unroll
    for (int r = 0; r < 8; ++r)
        a0[r] = *(const v4f*)&mrow[r * DIM];          // k4 = 0

    for (int k4 = 0; k4 < 32; k4 += 2) {
        // prefetch k4+1
#pragma unroll
        for (int r = 0; r < 8; ++r)
            a1[r] = *(const v4f*)&mrow[r * DIM + (k4 + 1) * 4];
        // compute k4 with a0
        {
            v4f bq[8];
#pragma unroll
            for (int u = 0; u < 4; ++u) {
                bq[u * 2]     = Wl4[(k4 * 4 + u) * 32 + j];
                bq[u * 2 + 1] = Wl4[(k4 * 4 + u) * 32 + 16 + j];
            }
#pragma unroll
            for (int u = 0; u < 4; ++u)
#pragma unroll
                for (int r = 0; r < 8; ++r) {
                    float av = a0[r][u];
#pragma unroll
                    for (int c = 0; c < 8; ++c)
                        acc[r][c] = fmaf(av, bq[u * 2 + (c >> 2)][c & 3], acc[r][c]);
                }
        }
        // prefetch k4+2
        if (k4 < 30) {
#pragma unroll
            for (int r = 0; r < 8; ++r)
                a0[r] = *(const v4f*)&mrow[r * DIM + (k4 + 2) * 4];
        }
        // compute k4+1 with a1
        {
            v4f bq[8];
#pragma unroll
            for (int u = 0; u < 4; ++u) {
                bq[u * 2]     = Wl4[((k4 + 1) * 4 + u) * 32 + j];
                bq[u * 2 + 1] = Wl4[((k4 + 1) * 4 + u) * 32 + 16 + j];
            }
#pragma unroll
            for (int u = 0; u < 4; ++u)
#pragma unroll
                for (int r = 0; r < 8; ++r) {
                    float av = a1[r][u];
#pragma unroll
                    for (int c = 0; c < 8; ++c)
                        acc[r][c] = fmaf(av, bq[u * 2 + (c >> 2)][c & 3], acc[r][c]);
                }
        }
    }

    // epilogue: BN + leakyReLU + store + optional fused dots
#pragma unroll
    for (int r = 0; r < 8; ++r) {
        int n = blockbase + i * 8 + r;
        float o[8];
#pragma unroll
        for (int c = 0; c < 8; ++c) {
            float y = acc[r][c] * A[c] + C[c];
            o[c] = y > 0.f ? y : 0.01f * y;
        }
        *(float4*)&h[(size_t)n * DIM + j * 8]     = *(float4*)&o[0];
        *(float4*)&h[(size_t)n * DIM + j * 8 + 4] = *(float4*)&o[4];
        if (fuse_dots) {
            float tr = 0.f, ts = 0.f;
#pragma unroll
            for (int c = 0; c < 8; ++c) {
                tr = fmaf(o[c], wrf[c], tr);
                ts = fmaf(o[c], wsf[c], ts);
            }
#pragma unroll
            for (int off = 1; off < 16; off <<= 1) {
                tr += __shfl_xor(tr, off);
                ts += __shfl_xor(ts, off);
            }
            if (j == 0) {
                tb[n] = tr;
                sb[n] = ts + pb0;
            }
        }
    }
}

// ---------------- score: sb[n] += sum_{e in(n)} tb[src] (4-wide batched) ----
__global__ void score_kernel(const int* __restrict__ rowptr, const int* __restrict__ csr_src,
                             const float* __restrict__ tb, float* __restrict__ sb) {
    int n = blockIdx.x * 256 + threadIdx.x;
    float s = sb[n];
    int e0 = rowptr[n], e1 = rowptr[n + 1];
    int e = e0;
    for (; e + 4 <= e1; e += 4) {
        float t0 = tb[csr_src[e]];
        float t1 = tb[csr_src[e + 1]];
        float t2 = tb[csr_src[e + 2]];
        float t3 = tb[csr_src[e + 3]];
        s += (t0 + t1) + (t2 + t3);
    }
    for (; e < e1; ++e) s += tb[csr_src[e]];
    sb[n] = s;
}

// ---------------- per-graph top-K via 4-pass radix select ----------------
__global__ __launch_bounds__(256) void select_kernel(const float* __restrict__ sb,
                                                     float* __restrict__ wsel) {
    __shared__ unsigned su[NPG];   // 32 KB
    __shared__ int hist[256];
    __shared__ int wsum[4];
    __shared__ unsigned pref_sh;
    __shared__ int kneed_sh;

    int b = blockIdx.x, t = threadIdx.x;
    int lane = t & 63, wv = t >> 6;
    const float* sc = &sb[b * NPG];
    for (int i = t; i < NPG; i += 256) {
        unsigned u = __float_as_uint(sc[i]);
        u = (u & 0x80000000u) ? ~u : (u | 0x80000000u);
        su[i] = u;
    }
    if (t == 0) { pref_sh = 0u; kneed_sh = KSEL; }
    __syncthreads();

    for (int p = 3; p >= 0; --p) {
        hist[t] = 0;
        __syncthreads();
        unsigned pref = pref_sh;
        int kneed = kneed_sh;
        int shift = p * 8;
        unsigned maskHi = (p == 3) ? 0u : (0xFFFFFFFFu << (shift + 8));
        for (int i = t; i < NPG; i += 256) {
            unsigned u = su[i];
            if ((u & maskHi) == (pref & maskHi))
                atomicAdd(&hist[(u >> shift) & 0xFFu], 1);
        }
        __syncthreads();
        int x = hist[t];
#pragma unroll
        for (int off = 1; off < 64; off <<= 1) {
            int y = __shfl_up(x, off);
            if (lane >= off) x += y;
        }
        if (lane == 63) wsum[wv] = x;
        __syncthreads();
        int add = 0, tot = 0;
#pragma unroll
        for (int jj = 0; jj < 4; ++jj) {
            int v = wsum[jj];
            tot += v;
            if (jj < wv) add += v;
        }
        int psum = x + add;
        int cnt_gt = tot - psum;
        int myh = hist[t];
        __syncthreads();
        if (cnt_gt < kneed && cnt_gt + myh >= kneed) {
            pref_sh = (pref & maskHi) | ((unsigned)t << shift);
            kneed_sh = kneed - cnt_gt;
        }
        __syncthreads();
    }
    unsigned T = pref_sh;
    int need_eq = kneed_sh;

    int base = t * 32;
    int local = 0;
#pragma unroll
    for (int k = 0; k < 32; ++k) local += (su[base + k] == T) ? 1 : 0;
    int x = local;
#pragma unroll
    for (int off = 1; off < 64; off <<= 1) {
        int y = __shfl_up(x, off);
        if (lane >= off) x += y;
    }
    if (lane == 63) wsum[wv] = x;
    __syncthreads();
    int add = 0;
#pragma unroll
    for (int jj = 0; jj < 4; ++jj)
        if (jj < wv) add += wsum[jj];
    int rank = (x - local) + add;
#pragma unroll
    for (int k = 0; k < 32; ++k) {
        unsigned u = su[base + k];
        bool take = (u > T);
        if (u == T) { take = (rank < need_eq); ++rank; }
        float w = 0.f;
        if (take) {
            float f = (u & 0x80000000u) ? __uint_as_float(u & 0x7FFFFFFFu)
                                        : __uint_as_float(~u);
            w = tanhf(f);
        }
        wsel[b * NPG + base + k] = w;
    }
}

// ---------------- weighted pool (XCD-aligned) ----------------
__global__ __launch_bounds__(256) void pool_kernel(const float* __restrict__ wsel,
                                                   const float* __restrict__ h,
                                                   float* __restrict__ part) {
    int xslot = blockIdx.x & 7, q = blockIdx.x >> 3;   // q: 0..63
    int b = xslot + ((q >= 32) ? 8 : 0);
    int ch = q & 31;
    int t = threadIdx.x;
    int nl = t >> 6;
    int l = t & 63;
    int n0 = b * NPG + ch * 256;
    float ax = 0.f, ay = 0.f;
    for (int i = nl; i < 256; i += 4) {
        int n = n0 + i;
        float w = wsel[n];
        if (w != 0.f) {
            float2 v = *(const float2*)&h[(size_t)n * DIM + l * 2];
            ax += w * v.x;
            ay += w * v.y;
        }
    }
    __shared__ float pp[4][DIM];
    pp[nl][l * 2] = ax;
    pp[nl][l * 2 + 1] = ay;
    __syncthreads();
    if (t < DIM) {
        float s = pp[0][t] + pp[1][t] + pp[2][t] + pp[3][t];
        part[((size_t)b * 32 + ch) * DIM + t] = s;
    }
}

__global__ void pool_reduce_kernel(const float* __restrict__ part,
                                   float* __restrict__ xg) {
    int b = blockIdx.x, d = threadIdx.x;
    float s = 0.f;
    for (int c = 0; c < 32; ++c) s += part[((size_t)b * 32 + c) * DIM + d];
    xg[b * DIM + d] = s;
}

// ---------------- final MLP ----------------
__global__ __launch_bounds__(1024) void mlp_kernel(const float* __restrict__ xg,
                                                   const float* __restrict__ r1w,
                                                   const float* __restrict__ r1b,
                                                   const float* __restrict__ r2w,
                                                   const float* __restrict__ r2b,
                                                   float* __restrict__ out) {
    __shared__ float h1[16 * 64];
    int t = threadIdx.x;
    {
        int b = t >> 6, j = t & 63;
        float acc = r1b[j];
        for (int k = 0; k < DIM; ++k) acc += xg[b * DIM + k] * r1w[k * 64 + j];
        h1[b * 64 + j] = acc > 0.f ? acc : 0.01f * acc;
    }
    __syncthreads();
    if (t < 64) {
        int b = t >> 2, o = t & 3;
        float acc = r2b[o];
        for (int k = 0; k < 64; ++k) acc += h1[b * 64 + k] * r2w[k * 4 + o];
        out[b * 4 + o] = acc;
    }
}

extern "C" void kernel_launch(void* const* d_in, const int* in_sizes, int n_in,
                              void* d_out, int out_size, void* d_ws, size_t ws_size,
                              hipStream_t stream) {
    const float* x       = (const float*)d_in[0];
    const int*   ei      = (const int*)d_in[2];
    const float* node_w  = (const float*)d_in[3];
    const float* node_b  = (const float*)d_in[4];
    const float* conv_w  = (const float*)d_in[7];
    const float* conv_b  = (const float*)d_in[8];
    const float* bn_g    = (const float*)d_in[9];
    const float* bn_b    = (const float*)d_in[10];
    const float* bn_m    = (const float*)d_in[11];
    const float* bn_v    = (const float*)d_in[12];
    const float* pool_wr = (const float*)d_in[13];
    const float* pool_ws = (const float*)d_in[14];
    const float* pool_b  = (const float*)d_in[15];
    const float* r1_w    = (const float*)d_in[16];
    const float* r1_b    = (const float*)d_in[17];
    const float* r2_w    = (const float*)d_in[18];
    const float* r2_b    = (const float*)d_in[19];
    float* out = (float*)d_out;

    char* ws = (char*)d_ws;
    size_t off = 0;
    auto alloc = [&](size_t bytes) {
        void* p = ws + off;
        off = (off + bytes + 255) & ~(size_t)255;
        return p;
    };
    float* h       = (float*)alloc((size_t)N_NODES * DIM * 4);
    float* mbuf    = (float*)alloc((size_t)N_NODES * DIM * 4);
    int*   deg     = (int*)alloc((size_t)N_NODES * 4);
    int*   rowptr  = (int*)alloc((size_t)(N_NODES + 1) * 4);
    int*   cursor  = (int*)alloc((size_t)N_NODES * 4);
    float* dis     = (float*)alloc((size_t)N_NODES * 4);
    int*   csr_src = (int*)alloc((size_t)E_EDGES * 4);
    float* csr_cf  = (float*)alloc((size_t)E_EDGES * 4);
    float* tb      = (float*)alloc((size_t)N_NODES * 4);
    float* sb      = (float*)alloc((size_t)N_NODES * 4);
    float* wsel    = (float*)alloc((size_t)N_NODES * 4);
    float* part    = (float*)alloc((size_t)NGRAPH * 32 * DIM * 4);
    float* xg      = (float*)alloc((size_t)NGRAPH * DIM * 4);
    int*   bsum    = (int*)alloc((size_t)SCAN_BLOCKS * 4);
    int*   boff    = (int*)alloc((size_t)SCAN_BLOCKS * 4);

    hipMemsetAsync(deg, 0, (size_t)N_NODES * 4, stream);
    count_deg_kernel<<<E_EDGES / 256, 256, 0, stream>>>(ei, deg);
    scan_partial_kernel<<<SCAN_BLOCKS, 256, 0, stream>>>(deg, bsum);
    scan_bsum_kernel<<<1, 128, 0, stream>>>(bsum, boff, rowptr);
    scan_final_kernel<<<SCAN_BLOCKS, 256, 0, stream>>>(deg, boff, rowptr, cursor, dis);
    fill_csr_kernel<<<E_EDGES / 256, 256, 0, stream>>>(ei, cursor, dis, csr_src, csr_cf);
    embed_kernel<<<N_NODES / 64, 256, 0, stream>>>(x, node_w, node_b, h);

    for (int layer = 0; layer < 3; ++layer) {
        agg_kernel<<<8192, 256, 0, stream>>>(h, rowptr, csr_src, csr_cf, dis, mbuf);
        gemm_bn_kernel<<<N_NODES / 256, 512, 0, stream>>>(
            mbuf, conv_w + (size_t)layer * DIM * DIM, conv_b + layer * DIM,
            bn_g + layer * DIM, bn_b + layer * DIM, bn_m + layer * DIM,
            bn_v + layer * DIM, h,
            pool_wr, pool_ws, pool_b, tb, sb, (layer == 2) ? 1 : 0);
    }

    score_kernel<<<N_NODES / 256, 256, 0, stream>>>(rowptr, csr_src, tb, sb);
    select_kernel<<<NGRAPH, 256, 0, stream>>>(sb, wsel);
    pool_kernel<<<NGRAPH * 32, 256, 0, stream>>>(wsel, h, part);
    pool_reduce_kernel<<<NGRAPH, DIM, 0, stream>>>(part, xg);
    mlp_kernel<<<1, 1024, 0, stream>>>(xg, r1_w, r1_b, r2_w, r2_b, out);
}

// Round 25
// 441.062 us; speedup vs baseline: 1.0983x; 1.0983x over previous
//
#include <hip/hip_runtime.h>

#define N_NODES 131072
#define E_EDGES 524288
#define NGRAPH  16
#define NPG     8192
#define DIM     128
#define KSEL    4096
#define SCAN_BLOCKS 128   // N_NODES / 1024

typedef float v2f __attribute__((ext_vector_type(2)));
typedef float v4f __attribute__((ext_vector_type(4)));

// ---------------- CSR build ----------------
__global__ void count_deg_kernel(const int* __restrict__ ei, int* __restrict__ deg) {
    int e = blockIdx.x * 256 + threadIdx.x;
    atomicAdd(&deg[ei[E_EDGES + e]], 1);
}

__global__ __launch_bounds__(256) void scan_partial_kernel(const int* __restrict__ deg,
                                                           int* __restrict__ bsum) {
    __shared__ int wsh[4];
    int b = blockIdx.x, t = threadIdx.x;
    int4 v = ((const int4*)&deg[b * 1024])[t];
    int s = v.x + v.y + v.z + v.w;
#pragma unroll
    for (int off = 32; off; off >>= 1) s += __shfl_xor(s, off);
    if ((t & 63) == 0) wsh[t >> 6] = s;
    __syncthreads();
    if (t == 0) bsum[b] = wsh[0] + wsh[1] + wsh[2] + wsh[3];
}

__global__ __launch_bounds__(128) void scan_bsum_kernel(const int* __restrict__ bsum,
                                                        int* __restrict__ boff,
                                                        int* __restrict__ rowptr) {
    __shared__ int w0;
    int t = threadIdx.x;
    int lane = t & 63;
    int v = bsum[t];
    int x = v;
#pragma unroll
    for (int off = 1; off < 64; off <<= 1) {
        int y = __shfl_up(x, off);
        if (lane >= off) x += y;
    }
    if (t == 63) w0 = x;
    __syncthreads();
    int incl = x + ((t >= 64) ? w0 : 0);
    boff[t] = incl - v;
    if (t == 127) rowptr[N_NODES] = incl;
}

__global__ __launch_bounds__(256) void scan_final_kernel(const int* __restrict__ deg,
                                                         const int* __restrict__ boff,
                                                         int* __restrict__ rowptr,
                                                         int* __restrict__ cursor,
                                                         float* __restrict__ dis) {
    __shared__ int wsum[4];
    int b = blockIdx.x, t = threadIdx.x;
    int lane = t & 63, wv = t >> 6;
    int4 v = ((const int4*)&deg[b * 1024])[t];
    int s = v.x + v.y + v.z + v.w;
    int x = s;
#pragma unroll
    for (int off = 1; off < 64; off <<= 1) {
        int y = __shfl_up(x, off);
        if (lane >= off) x += y;
    }
    if (lane == 63) wsum[wv] = x;
    __syncthreads();
    int add = boff[b];
#pragma unroll
    for (int j = 0; j < 4; ++j)
        if (j < wv) add += wsum[j];
    int excl = add + (x - s);
    int base = b * 1024 + t * 4;
    int4 rp;
    rp.x = excl;
    rp.y = excl + v.x;
    rp.z = rp.y + v.y;
    rp.w = rp.z + v.z;
    *(int4*)&rowptr[base] = rp;
    *(int4*)&cursor[base] = rp;
    float4 dv;
    dv.x = rsqrtf((float)v.x + 1.0f);
    dv.y = rsqrtf((float)v.y + 1.0f);
    dv.z = rsqrtf((float)v.z + 1.0f);
    dv.w = rsqrtf((float)v.w + 1.0f);
    *(float4*)&dis[base] = dv;
}

__global__ void fill_csr_kernel(const int* __restrict__ ei, int* __restrict__ cursor,
                                const float* __restrict__ dis, int* __restrict__ csr_src,
                                float* __restrict__ csr_coef) {
    int e = blockIdx.x * 256 + threadIdx.x;
    int s = ei[e];
    int d = ei[E_EDGES + e];
    int p = atomicAdd(&cursor[d], 1);
    csr_src[p] = s;
    csr_coef[p] = dis[s] * dis[d];
}

// ---------------- node embedding: h = x @ node_w + node_b (vectorized) ------
__global__ __launch_bounds__(256) void embed_kernel(const float* __restrict__ x,
                                                    const float* __restrict__ nw,
                                                    const float* __restrict__ nb,
                                                    float* __restrict__ h) {
    __shared__ float Wl[16 * DIM];
    __shared__ float biasl[DIM];
    int t = threadIdx.x;
    for (int i = t * 4; i < 16 * DIM; i += 1024)
        *(float4*)&Wl[i] = *(const float4*)&nw[i];
    if (t < 32) ((float4*)biasl)[t] = ((const float4*)nb)[t];
    __syncthreads();
    int xslot = blockIdx.x & 7, q = blockIdx.x >> 3;   // q: 0..255
    int g = xslot + ((q >= 128) ? 8 : 0);
    int chunk = q & 127;
    int base = g * NPG + chunk * 64;
    int nl = t >> 5;            // node_local 0..7
    int d4 = t & 31;            // float4 group 0..31
    v4f bias = ((const v4f*)biasl)[d4];
    const v4f* Wl4 = (const v4f*)Wl;
    for (int k = 0; k < 8; ++k) {
        int n = base + k * 8 + nl;
        const v4f* xr = (const v4f*)&x[n * 16];
        v4f x0 = xr[0], x1 = xr[1], x2 = xr[2], x3 = xr[3];
        v4f acc = bias;
#pragma unroll
        for (int u = 0; u < 4; ++u) {
            acc += x0[u] * Wl4[(u)      * 32 + d4];
            acc += x1[u] * Wl4[(u + 4)  * 32 + d4];
            acc += x2[u] * Wl4[(u + 8)  * 32 + d4];
            acc += x3[u] * Wl4[(u + 12) * 32 + d4];
        }
        *(v4f*)&h[(size_t)n * DIM + d4 * 4] = acc;
    }
}

// ---------------- sparse propagate: m = sum coef*h[src] + dis^2 * h ----------
// HALF-WAVE node pairing + float4 gathers: lane>>5 selects one of 2 concurrent
// nodes per wave; lane&31 covers dims ll*4..+3 (16B/lane, coalescing sweet
// spot). Each gather instruction services TWO edges (one per half-wave, 1KB);
// divergent edge loop runs max(lenA,lenB) ~ 5.3 iters instead of lenA+lenB=8
// per pair -> ~35% fewer dynamic instructions on the latency-bound path.
// 4-wide batching retained (8 rows in flight per wave). Normal m store (r17).
__global__ __launch_bounds__(256) void agg_kernel(const float* __restrict__ h,
                                                  const int* __restrict__ rowptr,
                                                  const int* __restrict__ csr_src,
                                                  const float* __restrict__ csr_coef,
                                                  const float* __restrict__ dis,
                                                  float* __restrict__ m) {
    int bb = blockIdx.x;
    int xslot = bb & 7;
    int c = bb >> 3;                 // 0..1023
    int g = xslot + ((c >= 512) ? 8 : 0);
    int chunk = c & 511;             // 0..511 (16 nodes each)
    int t = threadIdx.x;
    int w = t >> 6;                  // wave 0..3
    int lane = t & 63;
    int hw = lane >> 5;              // half-wave 0/1 -> node select
    int ll = lane & 31;              // dims ll*4 .. ll*4+3
    int nbase = g * NPG + chunk * 16;
#pragma unroll
    for (int it = 0; it < 2; ++it) {
        int n = nbase + it * 8 + w * 2 + hw;
        float dn = dis[n];
        v4f hv = *(const v4f*)&h[(size_t)n * DIM + ll * 4];
        v4f acc = (dn * dn) * hv;
        int e0 = rowptr[n], e1 = rowptr[n + 1];
        int e = e0;
        for (; e + 4 <= e1; e += 4) {
            int s0 = csr_src[e],     s1 = csr_src[e + 1];
            int s2 = csr_src[e + 2], s3 = csr_src[e + 3];
            float c0 = csr_coef[e],     c1 = csr_coef[e + 1];
            float c2 = csr_coef[e + 2], c3 = csr_coef[e + 3];
            v4f v0 = *(const v4f*)&h[(size_t)s0 * DIM + ll * 4];
            v4f v1 = *(const v4f*)&h[(size_t)s1 * DIM + ll * 4];
            v4f v2 = *(const v4f*)&h[(size_t)s2 * DIM + ll * 4];
            v4f v3 = *(const v4f*)&h[(size_t)s3 * DIM + ll * 4];
            acc += c0 * v0 + c1 * v1 + c2 * v2 + c3 * v3;
        }
        for (; e < e1; ++e) {
            int s = csr_src[e];
            float cf = csr_coef[e];
            v4f v = *(const v4f*)&h[(size_t)s * DIM + ll * 4];
            acc += cf * v;
        }
        *(v4f*)&m[(size_t)n * DIM + ll * 4] = acc;
    }
}

// ---------------- dense: h = leaky(BN(m @ W + cb)), optional fused dots ------
// FROZEN r17/r23 structure (67us validated): W-only LDS (64 KB, permuted
// rows -> conflict-free b128), 8x8 register tile, a-rows direct from global
// (L2-hot), a double-buffer, no k-loop barriers, (256,2) -> 128 VGPR.
// [Occupancy levers conclusively dead: zero-LDS r15, half-W r16, split-W r20,
//  (512,1) r24 (compiled clean but 2nd block never co-resided).]
__global__ __launch_bounds__(256, 2) void gemm_bn_kernel(const float* __restrict__ m,
                                                         const float* __restrict__ W,
                                                         const float* __restrict__ cb,
                                                         const float* __restrict__ bg,
                                                         const float* __restrict__ bb,
                                                         const float* __restrict__ bm,
                                                         const float* __restrict__ bv,
                                                         float* __restrict__ h,
                                                         const float* __restrict__ wr,
                                                         const float* __restrict__ ws,
                                                         const float* __restrict__ pb,
                                                         float* __restrict__ tb,
                                                         float* __restrict__ sb,
                                                         int fuse_dots) {
    __shared__ float Wl[DIM * DIM];   // 64 KB, permuted
    v4f* Wl4 = (v4f*)Wl;
    const int t = threadIdx.x;
    const int i = t >> 4;        // node group 0..15 (8 nodes each)
    const int j = t & 15;        // col group 0..15 (8 cols each)
    const int xslot = blockIdx.x & 7, q = blockIdx.x >> 3;   // q: 0..127
    const int graph = xslot + ((q >= 64) ? 8 : 0);
    const int chunk = q & 63;
    const int blockbase = graph * NPG + chunk * 128;

    // stage W permuted: dst slot = (c&1)*16 + (c>>1)
    {
        const v4f* W4 = (const v4f*)W;
#pragma unroll
        for (int p = 0; p < 16; ++p) {
            int idx = t + p * 256;
            int row = idx >> 5, c = idx & 31;
            Wl4[(row << 5) | ((c & 1) * 16 + (c >> 1))] = W4[idx];
        }
    }
    // BN consts for cols j*8 .. j*8+7
    float A[8], C[8];
#pragma unroll
    for (int c = 0; c < 8; ++c) {
        int d = j * 8 + c;
        float inv = rsqrtf(bv[d] + 1e-5f);
        float a = bg[d] * inv;
        A[c] = a;
        C[c] = (cb[d] - bm[d]) * a + bb[d];
    }
    float wrf[8], wsf[8];
    float pb0 = 0.f;
    if (fuse_dots) {
        *(float4*)&wrf[0] = ((const float4*)wr)[j * 2];
        *(float4*)&wrf[4] = ((const float4*)wr)[j * 2 + 1];
        *(float4*)&wsf[0] = ((const float4*)ws)[j * 2];
        *(float4*)&wsf[4] = ((const float4*)ws)[j * 2 + 1];
        pb0 = pb[0];
    }
    __syncthreads();

    const float* mrow = &m[(size_t)(blockbase + i * 8) * DIM];  // 8 rows, stride DIM

    float acc[8][8] = {{0.f}};
    v4f a0[8], a1[8];
#pragma unroll
    for (int r = 0; r < 8; ++r)
        a0[r] = *(const v4f*)&mrow[r * DIM];          // k4 = 0

    for (int k4 = 0; k4 < 32; k4 += 2) {
        // prefetch k4+1
#pragma unroll
        for (int r = 0; r < 8; ++r)
            a1[r] = *(const v4f*)&mrow[r * DIM + (k4 + 1) * 4];
        // compute k4 with a0
        {
            v4f bq[8];
#pragma unroll
            for (int u = 0; u < 4; ++u) {
                bq[u * 2]     = Wl4[(k4 * 4 + u) * 32 + j];
                bq[u * 2 + 1] = Wl4[(k4 * 4 + u) * 32 + 16 + j];
            }
#pragma unroll
            for (int u = 0; u < 4; ++u)
#pragma unroll
                for (int r = 0; r < 8; ++r) {
                    float av = a0[r][u];
#pragma unroll
                    for (int c = 0; c < 8; ++c)
                        acc[r][c] = fmaf(av, bq[u * 2 + (c >> 2)][c & 3], acc[r][c]);
                }
        }
        // prefetch k4+2
        if (k4 < 30) {
#pragma unroll
            for (int r = 0; r < 8; ++r)
                a0[r] = *(const v4f*)&mrow[r * DIM + (k4 + 2) * 4];
        }
        // compute k4+1 with a1
        {
            v4f bq[8];
#pragma unroll
            for (int u = 0; u < 4; ++u) {
                bq[u * 2]     = Wl4[((k4 + 1) * 4 + u) * 32 + j];
                bq[u * 2 + 1] = Wl4[((k4 + 1) * 4 + u) * 32 + 16 + j];
            }
#pragma unroll
            for (int u = 0; u < 4; ++u)
#pragma unroll
                for (int r = 0; r < 8; ++r) {
                    float av = a1[r][u];
#pragma unroll
                    for (int c = 0; c < 8; ++c)
                        acc[r][c] = fmaf(av, bq[u * 2 + (c >> 2)][c & 3], acc[r][c]);
                }
        }
    }

    // epilogue: BN + leakyReLU + store + optional fused dots
#pragma unroll
    for (int r = 0; r < 8; ++r) {
        int n = blockbase + i * 8 + r;
        float o[8];
#pragma unroll
        for (int c = 0; c < 8; ++c) {
            float y = acc[r][c] * A[c] + C[c];
            o[c] = y > 0.f ? y : 0.01f * y;
        }
        *(float4*)&h[(size_t)n * DIM + j * 8]     = *(float4*)&o[0];
        *(float4*)&h[(size_t)n * DIM + j * 8 + 4] = *(float4*)&o[4];
        if (fuse_dots) {
            float tr = 0.f, ts = 0.f;
#pragma unroll
            for (int c = 0; c < 8; ++c) {
                tr = fmaf(o[c], wrf[c], tr);
                ts = fmaf(o[c], wsf[c], ts);
            }
#pragma unroll
            for (int off = 1; off < 16; off <<= 1) {
                tr += __shfl_xor(tr, off);
                ts += __shfl_xor(ts, off);
            }
            if (j == 0) {
                tb[n] = tr;
                sb[n] = ts + pb0;
            }
        }
    }
}

// ---------------- score: sb[n] += sum_{e in(n)} tb[src] (4-wide batched) ----
__global__ void score_kernel(const int* __restrict__ rowptr, const int* __restrict__ csr_src,
                             const float* __restrict__ tb, float* __restrict__ sb) {
    int n = blockIdx.x * 256 + threadIdx.x;
    float s = sb[n];
    int e0 = rowptr[n], e1 = rowptr[n + 1];
    int e = e0;
    for (; e + 4 <= e1; e += 4) {
        float t0 = tb[csr_src[e]];
        float t1 = tb[csr_src[e + 1]];
        float t2 = tb[csr_src[e + 2]];
        float t3 = tb[csr_src[e + 3]];
        s += (t0 + t1) + (t2 + t3);
    }
    for (; e < e1; ++e) s += tb[csr_src[e]];
    sb[n] = s;
}

// ---------------- per-graph top-K via 4-pass radix select ----------------
__global__ __launch_bounds__(256) void select_kernel(const float* __restrict__ sb,
                                                     float* __restrict__ wsel) {
    __shared__ unsigned su[NPG];   // 32 KB
    __shared__ int hist[256];
    __shared__ int wsum[4];
    __shared__ unsigned pref_sh;
    __shared__ int kneed_sh;

    int b = blockIdx.x, t = threadIdx.x;
    int lane = t & 63, wv = t >> 6;
    const float* sc = &sb[b * NPG];
    for (int i = t; i < NPG; i += 256) {
        unsigned u = __float_as_uint(sc[i]);
        u = (u & 0x80000000u) ? ~u : (u | 0x80000000u);
        su[i] = u;
    }
    if (t == 0) { pref_sh = 0u; kneed_sh = KSEL; }
    __syncthreads();

    for (int p = 3; p >= 0; --p) {
        hist[t] = 0;
        __syncthreads();
        unsigned pref = pref_sh;
        int kneed = kneed_sh;
        int shift = p * 8;
        unsigned maskHi = (p == 3) ? 0u : (0xFFFFFFFFu << (shift + 8));
        for (int i = t; i < NPG; i += 256) {
            unsigned u = su[i];
            if ((u & maskHi) == (pref & maskHi))
                atomicAdd(&hist[(u >> shift) & 0xFFu], 1);
        }
        __syncthreads();
        int x = hist[t];
#pragma unroll
        for (int off = 1; off < 64; off <<= 1) {
            int y = __shfl_up(x, off);
            if (lane >= off) x += y;
        }
        if (lane == 63) wsum[wv] = x;
        __syncthreads();
        int add = 0, tot = 0;
#pragma unroll
        for (int jj = 0; jj < 4; ++jj) {
            int v = wsum[jj];
            tot += v;
            if (jj < wv) add += v;
        }
        int psum = x + add;
        int cnt_gt = tot - psum;
        int myh = hist[t];
        __syncthreads();
        if (cnt_gt < kneed && cnt_gt + myh >= kneed) {
            pref_sh = (pref & maskHi) | ((unsigned)t << shift);
            kneed_sh = kneed - cnt_gt;
        }
        __syncthreads();
    }
    unsigned T = pref_sh;
    int need_eq = kneed_sh;

    int base = t * 32;
    int local = 0;
#pragma unroll
    for (int k = 0; k < 32; ++k) local += (su[base + k] == T) ? 1 : 0;
    int x = local;
#pragma unroll
    for (int off = 1; off < 64; off <<= 1) {
        int y = __shfl_up(x, off);
        if (lane >= off) x += y;
    }
    if (lane == 63) wsum[wv] = x;
    __syncthreads();
    int add = 0;
#pragma unroll
    for (int jj = 0; jj < 4; ++jj)
        if (jj < wv) add += wsum[jj];
    int rank = (x - local) + add;
#pragma unroll
    for (int k = 0; k < 32; ++k) {
        unsigned u = su[base + k];
        bool take = (u > T);
        if (u == T) { take = (rank < need_eq); ++rank; }
        float w = 0.f;
        if (take) {
            float f = (u & 0x80000000u) ? __uint_as_float(u & 0x7FFFFFFFu)
                                        : __uint_as_float(~u);
            w = tanhf(f);
        }
        wsel[b * NPG + base + k] = w;
    }
}

// ---------------- weighted pool (XCD-aligned) ----------------
__global__ __launch_bounds__(256) void pool_kernel(const float* __restrict__ wsel,
                                                   const float* __restrict__ h,
                                                   float* __restrict__ part) {
    int xslot = blockIdx.x & 7, q = blockIdx.x >> 3;   // q: 0..63
    int b = xslot + ((q >= 32) ? 8 : 0);
    int ch = q & 31;
    int t = threadIdx.x;
    int nl = t >> 6;
    int l = t & 63;
    int n0 = b * NPG + ch * 256;
    float ax = 0.f, ay = 0.f;
    for (int i = nl; i < 256; i += 4) {
        int n = n0 + i;
        float w = wsel[n];
        if (w != 0.f) {
            float2 v = *(const float2*)&h[(size_t)n * DIM + l * 2];
            ax += w * v.x;
            ay += w * v.y;
        }
    }
    __shared__ float pp[4][DIM];
    pp[nl][l * 2] = ax;
    pp[nl][l * 2 + 1] = ay;
    __syncthreads();
    if (t < DIM) {
        float s = pp[0][t] + pp[1][t] + pp[2][t] + pp[3][t];
        part[((size_t)b * 32 + ch) * DIM + t] = s;
    }
}

__global__ void pool_reduce_kernel(const float* __restrict__ part,
                                   float* __restrict__ xg) {
    int b = blockIdx.x, d = threadIdx.x;
    float s = 0.f;
    for (int c = 0; c < 32; ++c) s += part[((size_t)b * 32 + c) * DIM + d];
    xg[b * DIM + d] = s;
}

// ---------------- final MLP ----------------
__global__ __launch_bounds__(1024) void mlp_kernel(const float* __restrict__ xg,
                                                   const float* __restrict__ r1w,
                                                   const float* __restrict__ r1b,
                                                   const float* __restrict__ r2w,
                                                   const float* __restrict__ r2b,
                                                   float* __restrict__ out) {
    __shared__ float h1[16 * 64];
    int t = threadIdx.x;
    {
        int b = t >> 6, j = t & 63;
        float acc = r1b[j];
        for (int k = 0; k < DIM; ++k) acc += xg[b * DIM + k] * r1w[k * 64 + j];
        h1[b * 64 + j] = acc > 0.f ? acc : 0.01f * acc;
    }
    __syncthreads();
    if (t < 64) {
        int b = t >> 2, o = t & 3;
        float acc = r2b[o];
        for (int k = 0; k < 64; ++k) acc += h1[b * 64 + k] * r2w[k * 4 + o];
        out[b * 4 + o] = acc;
    }
}

extern "C" void kernel_launch(void* const* d_in, const int* in_sizes, int n_in,
                              void* d_out, int out_size, void* d_ws, size_t ws_size,
                              hipStream_t stream) {
    const float* x       = (const float*)d_in[0];
    const int*   ei      = (const int*)d_in[2];
    const float* node_w  = (const float*)d_in[3];
    const float* node_b  = (const float*)d_in[4];
    const float* conv_w  = (const float*)d_in[7];
    const float* conv_b  = (const float*)d_in[8];
    const float* bn_g    = (const float*)d_in[9];
    const float* bn_b    = (const float*)d_in[10];
    const float* bn_m    = (const float*)d_in[11];
    const float* bn_v    = (const float*)d_in[12];
    const float* pool_wr = (const float*)d_in[13];
    const float* pool_ws = (const float*)d_in[14];
    const float* pool_b  = (const float*)d_in[15];
    const float* r1_w    = (const float*)d_in[16];
    const float* r1_b    = (const float*)d_in[17];
    const float* r2_w    = (const float*)d_in[18];
    const float* r2_b    = (const float*)d_in[19];
    float* out = (float*)d_out;

    char* ws = (char*)d_ws;
    size_t off = 0;
    auto alloc = [&](size_t bytes) {
        void* p = ws + off;
        off = (off + bytes + 255) & ~(size_t)255;
        return p;
    };
    float* h       = (float*)alloc((size_t)N_NODES * DIM * 4);
    float* mbuf    = (float*)alloc((size_t)N_NODES * DIM * 4);
    int*   deg     = (int*)alloc((size_t)N_NODES * 4);
    int*   rowptr  = (int*)alloc((size_t)(N_NODES + 1) * 4);
    int*   cursor  = (int*)alloc((size_t)N_NODES * 4);
    float* dis     = (float*)alloc((size_t)N_NODES * 4);
    int*   csr_src = (int*)alloc((size_t)E_EDGES * 4);
    float* csr_cf  = (float*)alloc((size_t)E_EDGES * 4);
    float* tb      = (float*)alloc((size_t)N_NODES * 4);
    float* sb      = (float*)alloc((size_t)N_NODES * 4);
    float* wsel    = (float*)alloc((size_t)N_NODES * 4);
    float* part    = (float*)alloc((size_t)NGRAPH * 32 * DIM * 4);
    float* xg      = (float*)alloc((size_t)NGRAPH * DIM * 4);
    int*   bsum    = (int*)alloc((size_t)SCAN_BLOCKS * 4);
    int*   boff    = (int*)alloc((size_t)SCAN_BLOCKS * 4);

    hipMemsetAsync(deg, 0, (size_t)N_NODES * 4, stream);
    count_deg_kernel<<<E_EDGES / 256, 256, 0, stream>>>(ei, deg);
    scan_partial_kernel<<<SCAN_BLOCKS, 256, 0, stream>>>(deg, bsum);
    scan_bsum_kernel<<<1, 128, 0, stream>>>(bsum, boff, rowptr);
    scan_final_kernel<<<SCAN_BLOCKS, 256, 0, stream>>>(deg, boff, rowptr, cursor, dis);
    fill_csr_kernel<<<E_EDGES / 256, 256, 0, stream>>>(ei, cursor, dis, csr_src, csr_cf);
    embed_kernel<<<N_NODES / 64, 256, 0, stream>>>(x, node_w, node_b, h);

    for (int layer = 0; layer < 3; ++layer) {
        agg_kernel<<<8192, 256, 0, stream>>>(h, rowptr, csr_src, csr_cf, dis, mbuf);
        gemm_bn_kernel<<<N_NODES / 128, 256, 0, stream>>>(
            mbuf, conv_w + (size_t)layer * DIM * DIM, conv_b + layer * DIM,
            bn_g + layer * DIM, bn_b + layer * DIM, bn_m + layer * DIM,
            bn_v + layer * DIM, h,
            pool_wr, pool_ws, pool_b, tb, sb, (layer == 2) ? 1 : 0);
    }

    score_kernel<<<N_NODES / 256, 256, 0, stream>>>(rowptr, csr_src, tb, sb);
    select_kernel<<<NGRAPH, 256, 0, stream>>>(sb, wsel);
    pool_kernel<<<NGRAPH * 32, 256, 0, stream>>>(wsel, h, part);
    pool_reduce_kernel<<<NGRAPH, DIM, 0, stream>>>(part, xg);
    mlp_kernel<<<1, 1024, 0, stream>>>(xg, r1_w, r1_b, r2_w, r2_b, out);
}

// Round 26
// 426.838 us; speedup vs baseline: 1.1349x; 1.0333x over previous
//
#include <hip/hip_runtime.h>

#define N_NODES 131072
#define E_EDGES 524288
#define NGRAPH  16
#define NPG     8192
#define DIM     128
#define KSEL    4096
#define SCAN_BLOCKS 128   // N_NODES / 1024

typedef float v2f __attribute__((ext_vector_type(2)));
typedef float v4f __attribute__((ext_vector_type(4)));

// ---------------- CSR build ----------------
__global__ void count_deg_kernel(const int* __restrict__ ei, int* __restrict__ deg) {
    int e = blockIdx.x * 256 + threadIdx.x;
    atomicAdd(&deg[ei[E_EDGES + e]], 1);
}

__global__ __launch_bounds__(256) void scan_partial_kernel(const int* __restrict__ deg,
                                                           int* __restrict__ bsum) {
    __shared__ int wsh[4];
    int b = blockIdx.x, t = threadIdx.x;
    int4 v = ((const int4*)&deg[b * 1024])[t];
    int s = v.x + v.y + v.z + v.w;
#pragma unroll
    for (int off = 32; off; off >>= 1) s += __shfl_xor(s, off);
    if ((t & 63) == 0) wsh[t >> 6] = s;
    __syncthreads();
    if (t == 0) bsum[b] = wsh[0] + wsh[1] + wsh[2] + wsh[3];
}

__global__ __launch_bounds__(128) void scan_bsum_kernel(const int* __restrict__ bsum,
                                                        int* __restrict__ boff,
                                                        int* __restrict__ rowptr) {
    __shared__ int w0;
    int t = threadIdx.x;
    int lane = t & 63;
    int v = bsum[t];
    int x = v;
#pragma unroll
    for (int off = 1; off < 64; off <<= 1) {
        int y = __shfl_up(x, off);
        if (lane >= off) x += y;
    }
    if (t == 63) w0 = x;
    __syncthreads();
    int incl = x + ((t >= 64) ? w0 : 0);
    boff[t] = incl - v;
    if (t == 127) rowptr[N_NODES] = incl;
}

__global__ __launch_bounds__(256) void scan_final_kernel(const int* __restrict__ deg,
                                                         const int* __restrict__ boff,
                                                         int* __restrict__ rowptr,
                                                         int* __restrict__ cursor,
                                                         float* __restrict__ dis) {
    __shared__ int wsum[4];
    int b = blockIdx.x, t = threadIdx.x;
    int lane = t & 63, wv = t >> 6;
    int4 v = ((const int4*)&deg[b * 1024])[t];
    int s = v.x + v.y + v.z + v.w;
    int x = s;
#pragma unroll
    for (int off = 1; off < 64; off <<= 1) {
        int y = __shfl_up(x, off);
        if (lane >= off) x += y;
    }
    if (lane == 63) wsum[wv] = x;
    __syncthreads();
    int add = boff[b];
#pragma unroll
    for (int j = 0; j < 4; ++j)
        if (j < wv) add += wsum[j];
    int excl = add + (x - s);
    int base = b * 1024 + t * 4;
    int4 rp;
    rp.x = excl;
    rp.y = excl + v.x;
    rp.z = rp.y + v.y;
    rp.w = rp.z + v.z;
    *(int4*)&rowptr[base] = rp;
    *(int4*)&cursor[base] = rp;
    float4 dv;
    dv.x = rsqrtf((float)v.x + 1.0f);
    dv.y = rsqrtf((float)v.y + 1.0f);
    dv.z = rsqrtf((float)v.z + 1.0f);
    dv.w = rsqrtf((float)v.w + 1.0f);
    *(float4*)&dis[base] = dv;
}

__global__ void fill_csr_kernel(const int* __restrict__ ei, int* __restrict__ cursor,
                                const float* __restrict__ dis, int* __restrict__ csr_src,
                                float* __restrict__ csr_coef) {
    int e = blockIdx.x * 256 + threadIdx.x;
    int s = ei[e];
    int d = ei[E_EDGES + e];
    int p = atomicAdd(&cursor[d], 1);
    csr_src[p] = s;
    csr_coef[p] = dis[s] * dis[d];
}

// ---------------- node embedding: h = x @ node_w + node_b (vectorized) ------
__global__ __launch_bounds__(256) void embed_kernel(const float* __restrict__ x,
                                                    const float* __restrict__ nw,
                                                    const float* __restrict__ nb,
                                                    float* __restrict__ h) {
    __shared__ float Wl[16 * DIM];
    __shared__ float biasl[DIM];
    int t = threadIdx.x;
    for (int i = t * 4; i < 16 * DIM; i += 1024)
        *(float4*)&Wl[i] = *(const float4*)&nw[i];
    if (t < 32) ((float4*)biasl)[t] = ((const float4*)nb)[t];
    __syncthreads();
    int xslot = blockIdx.x & 7, q = blockIdx.x >> 3;   // q: 0..255
    int g = xslot + ((q >= 128) ? 8 : 0);
    int chunk = q & 127;
    int base = g * NPG + chunk * 64;
    int nl = t >> 5;            // node_local 0..7
    int d4 = t & 31;            // float4 group 0..31
    v4f bias = ((const v4f*)biasl)[d4];
    const v4f* Wl4 = (const v4f*)Wl;
    for (int k = 0; k < 8; ++k) {
        int n = base + k * 8 + nl;
        const v4f* xr = (const v4f*)&x[n * 16];
        v4f x0 = xr[0], x1 = xr[1], x2 = xr[2], x3 = xr[3];
        v4f acc = bias;
#pragma unroll
        for (int u = 0; u < 4; ++u) {
            acc += x0[u] * Wl4[(u)      * 32 + d4];
            acc += x1[u] * Wl4[(u + 4)  * 32 + d4];
            acc += x2[u] * Wl4[(u + 8)  * 32 + d4];
            acc += x3[u] * Wl4[(u + 12) * 32 + d4];
        }
        *(v4f*)&h[(size_t)n * DIM + d4 * 4] = acc;
    }
}

// ---------------- sparse propagate: m = sum coef*h[src] + dis^2 * h ----------
// r25 validated (441us total): half-wave node pairing + float4 gathers,
// 4-wide edge batching, normal m store (r17), XCD-pinned graphs.
__global__ __launch_bounds__(256) void agg_kernel(const float* __restrict__ h,
                                                  const int* __restrict__ rowptr,
                                                  const int* __restrict__ csr_src,
                                                  const float* __restrict__ csr_coef,
                                                  const float* __restrict__ dis,
                                                  float* __restrict__ m) {
    int bb = blockIdx.x;
    int xslot = bb & 7;
    int c = bb >> 3;                 // 0..1023
    int g = xslot + ((c >= 512) ? 8 : 0);
    int chunk = c & 511;             // 0..511 (16 nodes each)
    int t = threadIdx.x;
    int w = t >> 6;                  // wave 0..3
    int lane = t & 63;
    int hw = lane >> 5;              // half-wave 0/1 -> node select
    int ll = lane & 31;              // dims ll*4 .. ll*4+3
    int nbase = g * NPG + chunk * 16;
#pragma unroll
    for (int it = 0; it < 2; ++it) {
        int n = nbase + it * 8 + w * 2 + hw;
        float dn = dis[n];
        v4f hv = *(const v4f*)&h[(size_t)n * DIM + ll * 4];
        v4f acc = (dn * dn) * hv;
        int e0 = rowptr[n], e1 = rowptr[n + 1];
        int e = e0;
        for (; e + 4 <= e1; e += 4) {
            int s0 = csr_src[e],     s1 = csr_src[e + 1];
            int s2 = csr_src[e + 2], s3 = csr_src[e + 3];
            float c0 = csr_coef[e],     c1 = csr_coef[e + 1];
            float c2 = csr_coef[e + 2], c3 = csr_coef[e + 3];
            v4f v0 = *(const v4f*)&h[(size_t)s0 * DIM + ll * 4];
            v4f v1 = *(const v4f*)&h[(size_t)s1 * DIM + ll * 4];
            v4f v2 = *(const v4f*)&h[(size_t)s2 * DIM + ll * 4];
            v4f v3 = *(const v4f*)&h[(size_t)s3 * DIM + ll * 4];
            acc += c0 * v0 + c1 * v1 + c2 * v2 + c3 * v3;
        }
        for (; e < e1; ++e) {
            int s = csr_src[e];
            float cf = csr_coef[e];
            v4f v = *(const v4f*)&h[(size_t)s * DIM + ll * 4];
            acc += cf * v;
        }
        *(v4f*)&m[(size_t)n * DIM + ll * 4] = acc;
    }
}

// ---------------- dense: h = leaky(BN(m @ W + cb)), optional fused dots ------
// FROZEN r17/r23 structure + T5 setprio around the k-loop: no barriers in the
// loop -> 8 independent waves/CU drift to different phases (some prefetching,
// some FMA-ing) -- the regime where setprio measured +4-7% (m191), not the
// lockstep regime where it nulled (m190).
__global__ __launch_bounds__(256, 2) void gemm_bn_kernel(const float* __restrict__ m,
                                                         const float* __restrict__ W,
                                                         const float* __restrict__ cb,
                                                         const float* __restrict__ bg,
                                                         const float* __restrict__ bb,
                                                         const float* __restrict__ bm,
                                                         const float* __restrict__ bv,
                                                         float* __restrict__ h,
                                                         const float* __restrict__ wr,
                                                         const float* __restrict__ ws,
                                                         const float* __restrict__ pb,
                                                         float* __restrict__ tb,
                                                         float* __restrict__ sb,
                                                         int fuse_dots) {
    __shared__ float Wl[DIM * DIM];   // 64 KB, permuted
    v4f* Wl4 = (v4f*)Wl;
    const int t = threadIdx.x;
    const int i = t >> 4;        // node group 0..15 (8 nodes each)
    const int j = t & 15;        // col group 0..15 (8 cols each)
    const int xslot = blockIdx.x & 7, q = blockIdx.x >> 3;   // q: 0..127
    const int graph = xslot + ((q >= 64) ? 8 : 0);
    const int chunk = q & 63;
    const int blockbase = graph * NPG + chunk * 128;

    // stage W permuted: dst slot = (c&1)*16 + (c>>1)
    {
        const v4f* W4 = (const v4f*)W;
#pragma unroll
        for (int p = 0; p < 16; ++p) {
            int idx = t + p * 256;
            int row = idx >> 5, c = idx & 31;
            Wl4[(row << 5) | ((c & 1) * 16 + (c >> 1))] = W4[idx];
        }
    }
    // BN consts for cols j*8 .. j*8+7
    float A[8], C[8];
#pragma unroll
    for (int c = 0; c < 8; ++c) {
        int d = j * 8 + c;
        float inv = rsqrtf(bv[d] + 1e-5f);
        float a = bg[d] * inv;
        A[c] = a;
        C[c] = (cb[d] - bm[d]) * a + bb[d];
    }
    float wrf[8], wsf[8];
    float pb0 = 0.f;
    if (fuse_dots) {
        *(float4*)&wrf[0] = ((const float4*)wr)[j * 2];
        *(float4*)&wrf[4] = ((const float4*)wr)[j * 2 + 1];
        *(float4*)&wsf[0] = ((const float4*)ws)[j * 2];
        *(float4*)&wsf[4] = ((const float4*)ws)[j * 2 + 1];
        pb0 = pb[0];
    }
    __syncthreads();

    const float* mrow = &m[(size_t)(blockbase + i * 8) * DIM];  // 8 rows, stride DIM

    float acc[8][8] = {{0.f}};
    v4f a0[8], a1[8];
#pragma unroll
    for (int r = 0; r < 8; ++r)
        a0[r] = *(const v4f*)&mrow[r * DIM];          // k4 = 0

    __builtin_amdgcn_s_setprio(1);
    for (int k4 = 0; k4 < 32; k4 += 2) {
        // prefetch k4+1
#pragma unroll
        for (int r = 0; r < 8; ++r)
            a1[r] = *(const v4f*)&mrow[r * DIM + (k4 + 1) * 4];
        // compute k4 with a0
        {
            v4f bq[8];
#pragma unroll
            for (int u = 0; u < 4; ++u) {
                bq[u * 2]     = Wl4[(k4 * 4 + u) * 32 + j];
                bq[u * 2 + 1] = Wl4[(k4 * 4 + u) * 32 + 16 + j];
            }
#pragma unroll
            for (int u = 0; u < 4; ++u)
#pragma unroll
                for (int r = 0; r < 8; ++r) {
                    float av = a0[r][u];
#pragma unroll
                    for (int c = 0; c < 8; ++c)
                        acc[r][c] = fmaf(av, bq[u * 2 + (c >> 2)][c & 3], acc[r][c]);
                }
        }
        // prefetch k4+2
        if (k4 < 30) {
#pragma unroll
            for (int r = 0; r < 8; ++r)
                a0[r] = *(const v4f*)&mrow[r * DIM + (k4 + 2) * 4];
        }
        // compute k4+1 with a1
        {
            v4f bq[8];
#pragma unroll
            for (int u = 0; u < 4; ++u) {
                bq[u * 2]     = Wl4[((k4 + 1) * 4 + u) * 32 + j];
                bq[u * 2 + 1] = Wl4[((k4 + 1) * 4 + u) * 32 + 16 + j];
            }
#pragma unroll
            for (int u = 0; u < 4; ++u)
#pragma unroll
                for (int r = 0; r < 8; ++r) {
                    float av = a1[r][u];
#pragma unroll
                    for (int c = 0; c < 8; ++c)
                        acc[r][c] = fmaf(av, bq[u * 2 + (c >> 2)][c & 3], acc[r][c]);
                }
        }
    }
    __builtin_amdgcn_s_setprio(0);

    // epilogue: BN + leakyReLU + store + optional fused dots
#pragma unroll
    for (int r = 0; r < 8; ++r) {
        int n = blockbase + i * 8 + r;
        float o[8];
#pragma unroll
        for (int c = 0; c < 8; ++c) {
            float y = acc[r][c] * A[c] + C[c];
            o[c] = y > 0.f ? y : 0.01f * y;
        }
        *(float4*)&h[(size_t)n * DIM + j * 8]     = *(float4*)&o[0];
        *(float4*)&h[(size_t)n * DIM + j * 8 + 4] = *(float4*)&o[4];
        if (fuse_dots) {
            float tr = 0.f, ts = 0.f;
#pragma unroll
            for (int c = 0; c < 8; ++c) {
                tr = fmaf(o[c], wrf[c], tr);
                ts = fmaf(o[c], wsf[c], ts);
            }
#pragma unroll
            for (int off = 1; off < 16; off <<= 1) {
                tr += __shfl_xor(tr, off);
                ts += __shfl_xor(ts, off);
            }
            if (j == 0) {
                tb[n] = tr;
                sb[n] = ts + pb0;
            }
        }
    }
}

// ---------------- score: sb[n] += sum_{e in(n)} tb[src] (4-wide batched) ----
__global__ void score_kernel(const int* __restrict__ rowptr, const int* __restrict__ csr_src,
                             const float* __restrict__ tb, float* __restrict__ sb) {
    int n = blockIdx.x * 256 + threadIdx.x;
    float s = sb[n];
    int e0 = rowptr[n], e1 = rowptr[n + 1];
    int e = e0;
    for (; e + 4 <= e1; e += 4) {
        float t0 = tb[csr_src[e]];
        float t1 = tb[csr_src[e + 1]];
        float t2 = tb[csr_src[e + 2]];
        float t3 = tb[csr_src[e + 3]];
        s += (t0 + t1) + (t2 + t3);
    }
    for (; e < e1; ++e) s += tb[csr_src[e]];
    sb[n] = s;
}

// ---------------- per-graph top-K via 4-pass radix select ----------------
__global__ __launch_bounds__(256) void select_kernel(const float* __restrict__ sb,
                                                     float* __restrict__ wsel) {
    __shared__ unsigned su[NPG];   // 32 KB
    __shared__ int hist[256];
    __shared__ int wsum[4];
    __shared__ unsigned pref_sh;
    __shared__ int kneed_sh;

    int b = blockIdx.x, t = threadIdx.x;
    int lane = t & 63, wv = t >> 6;
    const float* sc = &sb[b * NPG];
    for (int i = t; i < NPG; i += 256) {
        unsigned u = __float_as_uint(sc[i]);
        u = (u & 0x80000000u) ? ~u : (u | 0x80000000u);
        su[i] = u;
    }
    if (t == 0) { pref_sh = 0u; kneed_sh = KSEL; }
    __syncthreads();

    for (int p = 3; p >= 0; --p) {
        hist[t] = 0;
        __syncthreads();
        unsigned pref = pref_sh;
        int kneed = kneed_sh;
        int shift = p * 8;
        unsigned maskHi = (p == 3) ? 0u : (0xFFFFFFFFu << (shift + 8));
        for (int i = t; i < NPG; i += 256) {
            unsigned u = su[i];
            if ((u & maskHi) == (pref & maskHi))
                atomicAdd(&hist[(u >> shift) & 0xFFu], 1);
        }
        __syncthreads();
        int x = hist[t];
#pragma unroll
        for (int off = 1; off < 64; off <<= 1) {
            int y = __shfl_up(x, off);
            if (lane >= off) x += y;
        }
        if (lane == 63) wsum[wv] = x;
        __syncthreads();
        int add = 0, tot = 0;
#pragma unroll
        for (int jj = 0; jj < 4; ++jj) {
            int v = wsum[jj];
            tot += v;
            if (jj < wv) add += v;
        }
        int psum = x + add;
        int cnt_gt = tot - psum;
        int myh = hist[t];
        __syncthreads();
        if (cnt_gt < kneed && cnt_gt + myh >= kneed) {
            pref_sh = (pref & maskHi) | ((unsigned)t << shift);
            kneed_sh = kneed - cnt_gt;
        }
        __syncthreads();
    }
    unsigned T = pref_sh;
    int need_eq = kneed_sh;

    int base = t * 32;
    int local = 0;
#pragma unroll
    for (int k = 0; k < 32; ++k) local += (su[base + k] == T) ? 1 : 0;
    int x = local;
#pragma unroll
    for (int off = 1; off < 64; off <<= 1) {
        int y = __shfl_up(x, off);
        if (lane >= off) x += y;
    }
    if (lane == 63) wsum[wv] = x;
    __syncthreads();
    int add = 0;
#pragma unroll
    for (int jj = 0; jj < 4; ++jj)
        if (jj < wv) add += wsum[jj];
    int rank = (x - local) + add;
#pragma unroll
    for (int k = 0; k < 32; ++k) {
        unsigned u = su[base + k];
        bool take = (u > T);
        if (u == T) { take = (rank < need_eq); ++rank; }
        float w = 0.f;
        if (take) {
            float f = (u & 0x80000000u) ? __uint_as_float(u & 0x7FFFFFFFu)
                                        : __uint_as_float(~u);
            w = tanhf(f);
        }
        wsel[b * NPG + base + k] = w;
    }
}

// ---------------- weighted pool (half-wave v4f, XCD-aligned) ----------------
// r25 agg pattern ported: lane>>5 selects one of 2 concurrent nodes per wave,
// lane&31 covers dims ll*4..+3 (16B/lane); each load instruction services two
// nodes' rows -> ~half the dynamic memory instructions of the float2 version.
__global__ __launch_bounds__(256) void pool_kernel(const float* __restrict__ wsel,
                                                   const float* __restrict__ h,
                                                   float* __restrict__ part) {
    int xslot = blockIdx.x & 7, q = blockIdx.x >> 3;   // q: 0..63
    int b = xslot + ((q >= 32) ? 8 : 0);
    int ch = q & 31;
    int t = threadIdx.x;
    int w = t >> 6;              // wave 0..3
    int lane = t & 63;
    int hw = lane >> 5;          // half-wave node select
    int ll = lane & 31;          // dims ll*4 .. +3
    int n0 = b * NPG + ch * 256;
    v4f acc = {0.f, 0.f, 0.f, 0.f};
    for (int i = 0; i < 256; i += 8) {
        int n = n0 + i + w * 2 + hw;
        float wt = wsel[n];
        if (wt != 0.f) {
            v4f v = *(const v4f*)&h[(size_t)n * DIM + ll * 4];
            acc += wt * v;
        }
    }
    __shared__ float pp[8][DIM];
    *(v4f*)&pp[w * 2 + hw][ll * 4] = acc;
    __syncthreads();
    if (t < DIM) {
        float s = 0.f;
#pragma unroll
        for (int r = 0; r < 8; ++r) s += pp[r][t];
        part[((size_t)b * 32 + ch) * DIM + t] = s;
    }
}

__global__ void pool_reduce_kernel(const float* __restrict__ part,
                                   float* __restrict__ xg) {
    int b = blockIdx.x, d = threadIdx.x;
    float s = 0.f;
    for (int c = 0; c < 32; ++c) s += part[((size_t)b * 32 + c) * DIM + d];
    xg[b * DIM + d] = s;
}

// ---------------- final MLP ----------------
__global__ __launch_bounds__(1024) void mlp_kernel(const float* __restrict__ xg,
                                                   const float* __restrict__ r1w,
                                                   const float* __restrict__ r1b,
                                                   const float* __restrict__ r2w,
                                                   const float* __restrict__ r2b,
                                                   float* __restrict__ out) {
    __shared__ float h1[16 * 64];
    int t = threadIdx.x;
    {
        int b = t >> 6, j = t & 63;
        float acc = r1b[j];
        for (int k = 0; k < DIM; ++k) acc += xg[b * DIM + k] * r1w[k * 64 + j];
        h1[b * 64 + j] = acc > 0.f ? acc : 0.01f * acc;
    }
    __syncthreads();
    if (t < 64) {
        int b = t >> 2, o = t & 3;
        float acc = r2b[o];
        for (int k = 0; k < 64; ++k) acc += h1[b * 64 + k] * r2w[k * 4 + o];
        out[b * 4 + o] = acc;
    }
}

extern "C" void kernel_launch(void* const* d_in, const int* in_sizes, int n_in,
                              void* d_out, int out_size, void* d_ws, size_t ws_size,
                              hipStream_t stream) {
    const float* x       = (const float*)d_in[0];
    const int*   ei      = (const int*)d_in[2];
    const float* node_w  = (const float*)d_in[3];
    const float* node_b  = (const float*)d_in[4];
    const float* conv_w  = (const float*)d_in[7];
    const float* conv_b  = (const float*)d_in[8];
    const float* bn_g    = (const float*)d_in[9];
    const float* bn_b    = (const float*)d_in[10];
    const float* bn_m    = (const float*)d_in[11];
    const float* bn_v    = (const float*)d_in[12];
    const float* pool_wr = (const float*)d_in[13];
    const float* pool_ws = (const float*)d_in[14];
    const float* pool_b  = (const float*)d_in[15];
    const float* r1_w    = (const float*)d_in[16];
    const float* r1_b    = (const float*)d_in[17];
    const float* r2_w    = (const float*)d_in[18];
    const float* r2_b    = (const float*)d_in[19];
    float* out = (float*)d_out;

    char* ws = (char*)d_ws;
    size_t off = 0;
    auto alloc = [&](size_t bytes) {
        void* p = ws + off;
        off = (off + bytes + 255) & ~(size_t)255;
        return p;
    };
    float* h       = (float*)alloc((size_t)N_NODES * DIM * 4);
    float* mbuf    = (float*)alloc((size_t)N_NODES * DIM * 4);
    int*   deg     = (int*)alloc((size_t)N_NODES * 4);
    int*   rowptr  = (int*)alloc((size_t)(N_NODES + 1) * 4);
    int*   cursor  = (int*)alloc((size_t)N_NODES * 4);
    float* dis     = (float*)alloc((size_t)N_NODES * 4);
    int*   csr_src = (int*)alloc((size_t)E_EDGES * 4);
    float* csr_cf  = (float*)alloc((size_t)E_EDGES * 4);
    float* tb      = (float*)alloc((size_t)N_NODES * 4);
    float* sb      = (float*)alloc((size_t)N_NODES * 4);
    float* wsel    = (float*)alloc((size_t)N_NODES * 4);
    float* part    = (float*)alloc((size_t)NGRAPH * 32 * DIM * 4);
    float* xg      = (float*)alloc((size_t)NGRAPH * DIM * 4);
    int*   bsum    = (int*)alloc((size_t)SCAN_BLOCKS * 4);
    int*   boff    = (int*)alloc((size_t)SCAN_BLOCKS * 4);

    hipMemsetAsync(deg, 0, (size_t)N_NODES * 4, stream);
    count_deg_kernel<<<E_EDGES / 256, 256, 0, stream>>>(ei, deg);
    scan_partial_kernel<<<SCAN_BLOCKS, 256, 0, stream>>>(deg, bsum);
    scan_bsum_kernel<<<1, 128, 0, stream>>>(bsum, boff, rowptr);
    scan_final_kernel<<<SCAN_BLOCKS, 256, 0, stream>>>(deg, boff, rowptr, cursor, dis);
    fill_csr_kernel<<<E_EDGES / 256, 256, 0, stream>>>(ei, cursor, dis, csr_src, csr_cf);
    embed_kernel<<<N_NODES / 64, 256, 0, stream>>>(x, node_w, node_b, h);

    for (int layer = 0; layer < 3; ++layer) {
        agg_kernel<<<8192, 256, 0, stream>>>(h, rowptr, csr_src, csr_cf, dis, mbuf);
        gemm_bn_kernel<<<N_NODES / 128, 256, 0, stream>>>(
            mbuf, conv_w + (size_t)layer * DIM * DIM, conv_b + layer * DIM,
            bn_g + layer * DIM, bn_b + layer * DIM, bn_m + layer * DIM,
            bn_v + layer * DIM, h,
            pool_wr, pool_ws, pool_b, tb, sb, (layer == 2) ? 1 : 0);
    }

    score_kernel<<<N_NODES / 256, 256, 0, stream>>>(rowptr, csr_src, tb, sb);
    select_kernel<<<NGRAPH, 256, 0, stream>>>(sb, wsel);
    pool_kernel<<<NGRAPH * 32, 256, 0, stream>>>(wsel, h, part);
    pool_reduce_kernel<<<NGRAPH, DIM, 0, stream>>>(part, xg);
    mlp_kernel<<<1, 1024, 0, stream>>>(xg, r1_w, r1_b, r2_w, r2_b, out);
}

// Round 27
// 425.585 us; speedup vs baseline: 1.1383x; 1.0029x over previous
//
#include <hip/hip_runtime.h>

#define N_NODES 131072
#define E_EDGES 524288
#define NGRAPH  16
#define NPG     8192
#define DIM     128
#define KSEL    4096
#define SCAN_BLOCKS 128   // N_NODES / 1024

typedef float v2f __attribute__((ext_vector_type(2)));
typedef float v4f __attribute__((ext_vector_type(4)));

// ---------------- CSR build ----------------
__global__ void count_deg_kernel(const int* __restrict__ ei, int* __restrict__ deg) {
    int e = blockIdx.x * 256 + threadIdx.x;
    atomicAdd(&deg[ei[E_EDGES + e]], 1);
}

__global__ __launch_bounds__(256) void scan_partial_kernel(const int* __restrict__ deg,
                                                           int* __restrict__ bsum) {
    __shared__ int wsh[4];
    int b = blockIdx.x, t = threadIdx.x;
    int4 v = ((const int4*)&deg[b * 1024])[t];
    int s = v.x + v.y + v.z + v.w;
#pragma unroll
    for (int off = 32; off; off >>= 1) s += __shfl_xor(s, off);
    if ((t & 63) == 0) wsh[t >> 6] = s;
    __syncthreads();
    if (t == 0) bsum[b] = wsh[0] + wsh[1] + wsh[2] + wsh[3];
}

__global__ __launch_bounds__(128) void scan_bsum_kernel(const int* __restrict__ bsum,
                                                        int* __restrict__ boff,
                                                        int* __restrict__ rowptr) {
    __shared__ int w0;
    int t = threadIdx.x;
    int lane = t & 63;
    int v = bsum[t];
    int x = v;
#pragma unroll
    for (int off = 1; off < 64; off <<= 1) {
        int y = __shfl_up(x, off);
        if (lane >= off) x += y;
    }
    if (t == 63) w0 = x;
    __syncthreads();
    int incl = x + ((t >= 64) ? w0 : 0);
    boff[t] = incl - v;
    if (t == 127) rowptr[N_NODES] = incl;
}

__global__ __launch_bounds__(256) void scan_final_kernel(const int* __restrict__ deg,
                                                         const int* __restrict__ boff,
                                                         int* __restrict__ rowptr,
                                                         int* __restrict__ cursor,
                                                         float* __restrict__ dis) {
    __shared__ int wsum[4];
    int b = blockIdx.x, t = threadIdx.x;
    int lane = t & 63, wv = t >> 6;
    int4 v = ((const int4*)&deg[b * 1024])[t];
    int s = v.x + v.y + v.z + v.w;
    int x = s;
#pragma unroll
    for (int off = 1; off < 64; off <<= 1) {
        int y = __shfl_up(x, off);
        if (lane >= off) x += y;
    }
    if (lane == 63) wsum[wv] = x;
    __syncthreads();
    int add = boff[b];
#pragma unroll
    for (int j = 0; j < 4; ++j)
        if (j < wv) add += wsum[j];
    int excl = add + (x - s);
    int base = b * 1024 + t * 4;
    int4 rp;
    rp.x = excl;
    rp.y = excl + v.x;
    rp.z = rp.y + v.y;
    rp.w = rp.z + v.z;
    *(int4*)&rowptr[base] = rp;
    *(int4*)&cursor[base] = rp;
    float4 dv;
    dv.x = rsqrtf((float)v.x + 1.0f);
    dv.y = rsqrtf((float)v.y + 1.0f);
    dv.z = rsqrtf((float)v.z + 1.0f);
    dv.w = rsqrtf((float)v.w + 1.0f);
    *(float4*)&dis[base] = dv;
}

// packed edge record: {src, coef-bits} -> ONE 8-byte load per edge on the
// gather critical path (was two 4-byte loads from two arrays / cache lines).
__global__ void fill_csr_kernel(const int* __restrict__ ei, int* __restrict__ cursor,
                                const float* __restrict__ dis,
                                int2* __restrict__ csr_pack) {
    int e = blockIdx.x * 256 + threadIdx.x;
    int s = ei[e];
    int d = ei[E_EDGES + e];
    int p = atomicAdd(&cursor[d], 1);
    int2 pk;
    pk.x = s;
    pk.y = __float_as_int(dis[s] * dis[d]);
    csr_pack[p] = pk;
}

// ---------------- node embedding: h = x @ node_w + node_b (vectorized) ------
__global__ __launch_bounds__(256) void embed_kernel(const float* __restrict__ x,
                                                    const float* __restrict__ nw,
                                                    const float* __restrict__ nb,
                                                    float* __restrict__ h) {
    __shared__ float Wl[16 * DIM];
    __shared__ float biasl[DIM];
    int t = threadIdx.x;
    for (int i = t * 4; i < 16 * DIM; i += 1024)
        *(float4*)&Wl[i] = *(const float4*)&nw[i];
    if (t < 32) ((float4*)biasl)[t] = ((const float4*)nb)[t];
    __syncthreads();
    int xslot = blockIdx.x & 7, q = blockIdx.x >> 3;   // q: 0..255
    int g = xslot + ((q >= 128) ? 8 : 0);
    int chunk = q & 127;
    int base = g * NPG + chunk * 64;
    int nl = t >> 5;            // node_local 0..7
    int d4 = t & 31;            // float4 group 0..31
    v4f bias = ((const v4f*)biasl)[d4];
    const v4f* Wl4 = (const v4f*)Wl;
    for (int k = 0; k < 8; ++k) {
        int n = base + k * 8 + nl;
        const v4f* xr = (const v4f*)&x[n * 16];
        v4f x0 = xr[0], x1 = xr[1], x2 = xr[2], x3 = xr[3];
        v4f acc = bias;
#pragma unroll
        for (int u = 0; u < 4; ++u) {
            acc += x0[u] * Wl4[(u)      * 32 + d4];
            acc += x1[u] * Wl4[(u + 4)  * 32 + d4];
            acc += x2[u] * Wl4[(u + 8)  * 32 + d4];
            acc += x3[u] * Wl4[(u + 12) * 32 + d4];
        }
        *(v4f*)&h[(size_t)n * DIM + d4 * 4] = acc;
    }
}

// ---------------- sparse propagate: m = sum coef*h[src] + dis^2 * h ----------
// r25/r26 validated structure + packed edges: half-wave node pairing, float4
// gathers, 4-wide batching (now 4 x int2 loads), normal m store, XCD-pinned.
__global__ __launch_bounds__(256) void agg_kernel(const float* __restrict__ h,
                                                  const int* __restrict__ rowptr,
                                                  const int2* __restrict__ csr_pack,
                                                  const float* __restrict__ dis,
                                                  float* __restrict__ m) {
    int bb = blockIdx.x;
    int xslot = bb & 7;
    int c = bb >> 3;                 // 0..1023
    int g = xslot + ((c >= 512) ? 8 : 0);
    int chunk = c & 511;             // 0..511 (16 nodes each)
    int t = threadIdx.x;
    int w = t >> 6;                  // wave 0..3
    int lane = t & 63;
    int hw = lane >> 5;              // half-wave 0/1 -> node select
    int ll = lane & 31;              // dims ll*4 .. ll*4+3
    int nbase = g * NPG + chunk * 16;
#pragma unroll
    for (int it = 0; it < 2; ++it) {
        int n = nbase + it * 8 + w * 2 + hw;
        float dn = dis[n];
        v4f hv = *(const v4f*)&h[(size_t)n * DIM + ll * 4];
        v4f acc = (dn * dn) * hv;
        int e0 = rowptr[n], e1 = rowptr[n + 1];
        int e = e0;
        for (; e + 4 <= e1; e += 4) {
            int2 p0 = csr_pack[e],     p1 = csr_pack[e + 1];
            int2 p2 = csr_pack[e + 2], p3 = csr_pack[e + 3];
            float c0 = __int_as_float(p0.y), c1 = __int_as_float(p1.y);
            float c2 = __int_as_float(p2.y), c3 = __int_as_float(p3.y);
            v4f v0 = *(const v4f*)&h[(size_t)p0.x * DIM + ll * 4];
            v4f v1 = *(const v4f*)&h[(size_t)p1.x * DIM + ll * 4];
            v4f v2 = *(const v4f*)&h[(size_t)p2.x * DIM + ll * 4];
            v4f v3 = *(const v4f*)&h[(size_t)p3.x * DIM + ll * 4];
            acc += c0 * v0 + c1 * v1 + c2 * v2 + c3 * v3;
        }
        for (; e < e1; ++e) {
            int2 p = csr_pack[e];
            float cf = __int_as_float(p.y);
            v4f v = *(const v4f*)&h[(size_t)p.x * DIM + ll * 4];
            acc += cf * v;
        }
        *(v4f*)&m[(size_t)n * DIM + ll * 4] = acc;
    }
}

// ---------------- dense: h = leaky(BN(m @ W + cb)), optional fused dots ------
// FROZEN r17/r23 structure + T5 setprio (r26 validated: 65.5us).
__global__ __launch_bounds__(256, 2) void gemm_bn_kernel(const float* __restrict__ m,
                                                         const float* __restrict__ W,
                                                         const float* __restrict__ cb,
                                                         const float* __restrict__ bg,
                                                         const float* __restrict__ bb,
                                                         const float* __restrict__ bm,
                                                         const float* __restrict__ bv,
                                                         float* __restrict__ h,
                                                         const float* __restrict__ wr,
                                                         const float* __restrict__ ws,
                                                         const float* __restrict__ pb,
                                                         float* __restrict__ tb,
                                                         float* __restrict__ sb,
                                                         int fuse_dots) {
    __shared__ float Wl[DIM * DIM];   // 64 KB, permuted
    v4f* Wl4 = (v4f*)Wl;
    const int t = threadIdx.x;
    const int i = t >> 4;        // node group 0..15 (8 nodes each)
    const int j = t & 15;        // col group 0..15 (8 cols each)
    const int xslot = blockIdx.x & 7, q = blockIdx.x >> 3;   // q: 0..127
    const int graph = xslot + ((q >= 64) ? 8 : 0);
    const int chunk = q & 63;
    const int blockbase = graph * NPG + chunk * 128;

    // stage W permuted: dst slot = (c&1)*16 + (c>>1)
    {
        const v4f* W4 = (const v4f*)W;
#pragma unroll
        for (int p = 0; p < 16; ++p) {
            int idx = t + p * 256;
            int row = idx >> 5, c = idx & 31;
            Wl4[(row << 5) | ((c & 1) * 16 + (c >> 1))] = W4[idx];
        }
    }
    // BN consts for cols j*8 .. j*8+7
    float A[8], C[8];
#pragma unroll
    for (int c = 0; c < 8; ++c) {
        int d = j * 8 + c;
        float inv = rsqrtf(bv[d] + 1e-5f);
        float a = bg[d] * inv;
        A[c] = a;
        C[c] = (cb[d] - bm[d]) * a + bb[d];
    }
    float wrf[8], wsf[8];
    float pb0 = 0.f;
    if (fuse_dots) {
        *(float4*)&wrf[0] = ((const float4*)wr)[j * 2];
        *(float4*)&wrf[4] = ((const float4*)wr)[j * 2 + 1];
        *(float4*)&wsf[0] = ((const float4*)ws)[j * 2];
        *(float4*)&wsf[4] = ((const float4*)ws)[j * 2 + 1];
        pb0 = pb[0];
    }
    __syncthreads();

    const float* mrow = &m[(size_t)(blockbase + i * 8) * DIM];  // 8 rows, stride DIM

    float acc[8][8] = {{0.f}};
    v4f a0[8], a1[8];
#pragma unroll
    for (int r = 0; r < 8; ++r)
        a0[r] = *(const v4f*)&mrow[r * DIM];          // k4 = 0

    __builtin_amdgcn_s_setprio(1);
    for (int k4 = 0; k4 < 32; k4 += 2) {
        // prefetch k4+1
#pragma unroll
        for (int r = 0; r < 8; ++r)
            a1[r] = *(const v4f*)&mrow[r * DIM + (k4 + 1) * 4];
        // compute k4 with a0
        {
            v4f bq[8];
#pragma unroll
            for (int u = 0; u < 4; ++u) {
                bq[u * 2]     = Wl4[(k4 * 4 + u) * 32 + j];
                bq[u * 2 + 1] = Wl4[(k4 * 4 + u) * 32 + 16 + j];
            }
#pragma unroll
            for (int u = 0; u < 4; ++u)
#pragma unroll
                for (int r = 0; r < 8; ++r) {
                    float av = a0[r][u];
#pragma unroll
                    for (int c = 0; c < 8; ++c)
                        acc[r][c] = fmaf(av, bq[u * 2 + (c >> 2)][c & 3], acc[r][c]);
                }
        }
        // prefetch k4+2
        if (k4 < 30) {
#pragma unroll
            for (int r = 0; r < 8; ++r)
                a0[r] = *(const v4f*)&mrow[r * DIM + (k4 + 2) * 4];
        }
        // compute k4+1 with a1
        {
            v4f bq[8];
#pragma unroll
            for (int u = 0; u < 4; ++u) {
                bq[u * 2]     = Wl4[((k4 + 1) * 4 + u) * 32 + j];
                bq[u * 2 + 1] = Wl4[((k4 + 1) * 4 + u) * 32 + 16 + j];
            }
#pragma unroll
            for (int u = 0; u < 4; ++u)
#pragma unroll
                for (int r = 0; r < 8; ++r) {
                    float av = a1[r][u];
#pragma unroll
                    for (int c = 0; c < 8; ++c)
                        acc[r][c] = fmaf(av, bq[u * 2 + (c >> 2)][c & 3], acc[r][c]);
                }
        }
    }
    __builtin_amdgcn_s_setprio(0);

    // epilogue: BN + leakyReLU + store + optional fused dots
#pragma unroll
    for (int r = 0; r < 8; ++r) {
        int n = blockbase + i * 8 + r;
        float o[8];
#pragma unroll
        for (int c = 0; c < 8; ++c) {
            float y = acc[r][c] * A[c] + C[c];
            o[c] = y > 0.f ? y : 0.01f * y;
        }
        *(float4*)&h[(size_t)n * DIM + j * 8]     = *(float4*)&o[0];
        *(float4*)&h[(size_t)n * DIM + j * 8 + 4] = *(float4*)&o[4];
        if (fuse_dots) {
            float tr = 0.f, ts = 0.f;
#pragma unroll
            for (int c = 0; c < 8; ++c) {
                tr = fmaf(o[c], wrf[c], tr);
                ts = fmaf(o[c], wsf[c], ts);
            }
#pragma unroll
            for (int off = 1; off < 16; off <<= 1) {
                tr += __shfl_xor(tr, off);
                ts += __shfl_xor(ts, off);
            }
            if (j == 0) {
                tb[n] = tr;
                sb[n] = ts + pb0;
            }
        }
    }
}

// ---------------- score: sb[n] += sum_{e in(n)} tb[src] (packed, batched) ----
__global__ void score_kernel(const int* __restrict__ rowptr,
                             const int2* __restrict__ csr_pack,
                             const float* __restrict__ tb, float* __restrict__ sb) {
    int n = blockIdx.x * 256 + threadIdx.x;
    float s = sb[n];
    int e0 = rowptr[n], e1 = rowptr[n + 1];
    int e = e0;
    for (; e + 4 <= e1; e += 4) {
        int s0 = csr_pack[e].x, s1 = csr_pack[e + 1].x;
        int s2 = csr_pack[e + 2].x, s3 = csr_pack[e + 3].x;
        float t0 = tb[s0], t1 = tb[s1], t2 = tb[s2], t3 = tb[s3];
        s += (t0 + t1) + (t2 + t3);
    }
    for (; e < e1; ++e) s += tb[csr_pack[e].x];
    sb[n] = s;
}

// ---------------- per-graph top-K via 4-pass radix select ----------------
__global__ __launch_bounds__(256) void select_kernel(const float* __restrict__ sb,
                                                     float* __restrict__ wsel) {
    __shared__ unsigned su[NPG];   // 32 KB
    __shared__ int hist[256];
    __shared__ int wsum[4];
    __shared__ unsigned pref_sh;
    __shared__ int kneed_sh;

    int b = blockIdx.x, t = threadIdx.x;
    int lane = t & 63, wv = t >> 6;
    const float* sc = &sb[b * NPG];
    for (int i = t; i < NPG; i += 256) {
        unsigned u = __float_as_uint(sc[i]);
        u = (u & 0x80000000u) ? ~u : (u | 0x80000000u);
        su[i] = u;
    }
    if (t == 0) { pref_sh = 0u; kneed_sh = KSEL; }
    __syncthreads();

    for (int p = 3; p >= 0; --p) {
        hist[t] = 0;
        __syncthreads();
        unsigned pref = pref_sh;
        int kneed = kneed_sh;
        int shift = p * 8;
        unsigned maskHi = (p == 3) ? 0u : (0xFFFFFFFFu << (shift + 8));
        for (int i = t; i < NPG; i += 256) {
            unsigned u = su[i];
            if ((u & maskHi) == (pref & maskHi))
                atomicAdd(&hist[(u >> shift) & 0xFFu], 1);
        }
        __syncthreads();
        int x = hist[t];
#pragma unroll
        for (int off = 1; off < 64; off <<= 1) {
            int y = __shfl_up(x, off);
            if (lane >= off) x += y;
        }
        if (lane == 63) wsum[wv] = x;
        __syncthreads();
        int add = 0, tot = 0;
#pragma unroll
        for (int jj = 0; jj < 4; ++jj) {
            int v = wsum[jj];
            tot += v;
            if (jj < wv) add += v;
        }
        int psum = x + add;
        int cnt_gt = tot - psum;
        int myh = hist[t];
        __syncthreads();
        if (cnt_gt < kneed && cnt_gt + myh >= kneed) {
            pref_sh = (pref & maskHi) | ((unsigned)t << shift);
            kneed_sh = kneed - cnt_gt;
        }
        __syncthreads();
    }
    unsigned T = pref_sh;
    int need_eq = kneed_sh;

    int base = t * 32;
    int local = 0;
#pragma unroll
    for (int k = 0; k < 32; ++k) local += (su[base + k] == T) ? 1 : 0;
    int x = local;
#pragma unroll
    for (int off = 1; off < 64; off <<= 1) {
        int y = __shfl_up(x, off);
        if (lane >= off) x += y;
    }
    if (lane == 63) wsum[wv] = x;
    __syncthreads();
    int add = 0;
#pragma unroll
    for (int jj = 0; jj < 4; ++jj)
        if (jj < wv) add += wsum[jj];
    int rank = (x - local) + add;
#pragma unroll
    for (int k = 0; k < 32; ++k) {
        unsigned u = su[base + k];
        bool take = (u > T);
        if (u == T) { take = (rank < need_eq); ++rank; }
        float w = 0.f;
        if (take) {
            float f = (u & 0x80000000u) ? __uint_as_float(u & 0x7FFFFFFFu)
                                        : __uint_as_float(~u);
            w = tanhf(f);
        }
        wsel[b * NPG + base + k] = w;
    }
}

// ---------------- weighted pool (half-wave v4f, XCD-aligned) ----------------
__global__ __launch_bounds__(256) void pool_kernel(const float* __restrict__ wsel,
                                                   const float* __restrict__ h,
                                                   float* __restrict__ part) {
    int xslot = blockIdx.x & 7, q = blockIdx.x >> 3;   // q: 0..63
    int b = xslot + ((q >= 32) ? 8 : 0);
    int ch = q & 31;
    int t = threadIdx.x;
    int w = t >> 6;              // wave 0..3
    int lane = t & 63;
    int hw = lane >> 5;          // half-wave node select
    int ll = lane & 31;          // dims ll*4 .. +3
    int n0 = b * NPG + ch * 256;
    v4f acc = {0.f, 0.f, 0.f, 0.f};
    for (int i = 0; i < 256; i += 8) {
        int n = n0 + i + w * 2 + hw;
        float wt = wsel[n];
        if (wt != 0.f) {
            v4f v = *(const v4f*)&h[(size_t)n * DIM + ll * 4];
            acc += wt * v;
        }
    }
    __shared__ float pp[8][DIM];
    *(v4f*)&pp[w * 2 + hw][ll * 4] = acc;
    __syncthreads();
    if (t < DIM) {
        float s = 0.f;
#pragma unroll
        for (int r = 0; r < 8; ++r) s += pp[r][t];
        part[((size_t)b * 32 + ch) * DIM + t] = s;
    }
}

__global__ void pool_reduce_kernel(const float* __restrict__ part,
                                   float* __restrict__ xg) {
    int b = blockIdx.x, d = threadIdx.x;
    float s = 0.f;
    for (int c = 0; c < 32; ++c) s += part[((size_t)b * 32 + c) * DIM + d];
    xg[b * DIM + d] = s;
}

// ---------------- final MLP ----------------
__global__ __launch_bounds__(1024) void mlp_kernel(const float* __restrict__ xg,
                                                   const float* __restrict__ r1w,
                                                   const float* __restrict__ r1b,
                                                   const float* __restrict__ r2w,
                                                   const float* __restrict__ r2b,
                                                   float* __restrict__ out) {
    __shared__ float h1[16 * 64];
    int t = threadIdx.x;
    {
        int b = t >> 6, j = t & 63;
        float acc = r1b[j];
        for (int k = 0; k < DIM; ++k) acc += xg[b * DIM + k] * r1w[k * 64 + j];
        h1[b * 64 + j] = acc > 0.f ? acc : 0.01f * acc;
    }
    __syncthreads();
    if (t < 64) {
        int b = t >> 2, o = t & 3;
        float acc = r2b[o];
        for (int k = 0; k < 64; ++k) acc += h1[b * 64 + k] * r2w[k * 4 + o];
        out[b * 4 + o] = acc;
    }
}

extern "C" void kernel_launch(void* const* d_in, const int* in_sizes, int n_in,
                              void* d_out, int out_size, void* d_ws, size_t ws_size,
                              hipStream_t stream) {
    const float* x       = (const float*)d_in[0];
    const int*   ei      = (const int*)d_in[2];
    const float* node_w  = (const float*)d_in[3];
    const float* node_b  = (const float*)d_in[4];
    const float* conv_w  = (const float*)d_in[7];
    const float* conv_b  = (const float*)d_in[8];
    const float* bn_g    = (const float*)d_in[9];
    const float* bn_b    = (const float*)d_in[10];
    const float* bn_m    = (const float*)d_in[11];
    const float* bn_v    = (const float*)d_in[12];
    const float* pool_wr = (const float*)d_in[13];
    const float* pool_ws = (const float*)d_in[14];
    const float* pool_b  = (const float*)d_in[15];
    const float* r1_w    = (const float*)d_in[16];
    const float* r1_b    = (const float*)d_in[17];
    const float* r2_w    = (const float*)d_in[18];
    const float* r2_b    = (const float*)d_in[19];
    float* out = (float*)d_out;

    char* ws = (char*)d_ws;
    size_t off = 0;
    auto alloc = [&](size_t bytes) {
        void* p = ws + off;
        off = (off + bytes + 255) & ~(size_t)255;
        return p;
    };
    float* h        = (float*)alloc((size_t)N_NODES * DIM * 4);
    float* mbuf     = (float*)alloc((size_t)N_NODES * DIM * 4);
    int*   deg      = (int*)alloc((size_t)N_NODES * 4);
    int*   rowptr   = (int*)alloc((size_t)(N_NODES + 1) * 4);
    int*   cursor   = (int*)alloc((size_t)N_NODES * 4);
    float* dis      = (float*)alloc((size_t)N_NODES * 4);
    int2*  csr_pack = (int2*)alloc((size_t)E_EDGES * 8);
    float* tb       = (float*)alloc((size_t)N_NODES * 4);
    float* sb       = (float*)alloc((size_t)N_NODES * 4);
    float* wsel     = (float*)alloc((size_t)N_NODES * 4);
    float* part     = (float*)alloc((size_t)NGRAPH * 32 * DIM * 4);
    float* xg       = (float*)alloc((size_t)NGRAPH * DIM * 4);
    int*   bsum     = (int*)alloc((size_t)SCAN_BLOCKS * 4);
    int*   boff     = (int*)alloc((size_t)SCAN_BLOCKS * 4);

    hipMemsetAsync(deg, 0, (size_t)N_NODES * 4, stream);
    count_deg_kernel<<<E_EDGES / 256, 256, 0, stream>>>(ei, deg);
    scan_partial_kernel<<<SCAN_BLOCKS, 256, 0, stream>>>(deg, bsum);
    scan_bsum_kernel<<<1, 128, 0, stream>>>(bsum, boff, rowptr);
    scan_final_kernel<<<SCAN_BLOCKS, 256, 0, stream>>>(deg, boff, rowptr, cursor, dis);
    fill_csr_kernel<<<E_EDGES / 256, 256, 0, stream>>>(ei, cursor, dis, csr_pack);
    embed_kernel<<<N_NODES / 64, 256, 0, stream>>>(x, node_w, node_b, h);

    for (int layer = 0; layer < 3; ++layer) {
        agg_kernel<<<8192, 256, 0, stream>>>(h, rowptr, csr_pack, dis, mbuf);
        gemm_bn_kernel<<<N_NODES / 128, 256, 0, stream>>>(
            mbuf, conv_w + (size_t)layer * DIM * DIM, conv_b + layer * DIM,
            bn_g + layer * DIM, bn_b + layer * DIM, bn_m + layer * DIM,
            bn_v + layer * DIM, h,
            pool_wr, pool_ws, pool_b, tb, sb, (layer == 2) ? 1 : 0);
    }

    score_kernel<<<N_NODES / 256, 256, 0, stream>>>(rowptr, csr_pack, tb, sb);
    select_kernel<<<NGRAPH, 256, 0, stream>>>(sb, wsel);
    pool_kernel<<<NGRAPH * 32, 256, 0, stream>>>(wsel, h, part);
    pool_reduce_kernel<<<NGRAPH, DIM, 0, stream>>>(part, xg);
    mlp_kernel<<<1, 1024, 0, stream>>>(xg, r1_w, r1_b, r2_w, r2_b, out);
}